// Round 17
// baseline (777.822 us; speedup 1.0000x reference)
//
#include <hip/hip_runtime.h>
#include <hip/hip_fp16.h>
#include <cstdint>
#include <cstddef>

#define NN 4096
#define EE 131072
#define TS 64

__device__ __forceinline__ unsigned fkey(float f) {
    unsigned u = __float_as_uint(f);
    return (u & 0x80000000u) ? ~u : (u | 0x80000000u);
}
__device__ __forceinline__ float funkey(unsigned k) {
    unsigned u = (k & 0x80000000u) ? (k & 0x7fffffffu) : ~k;
    return __uint_as_float(u);
}

// ---- VALU-only asm pins (no SALU/SCC writes; proven safe rounds 14-16) ----
__device__ __forceinline__ void pkmax(unsigned& a, unsigned x) {
    asm("v_pk_max_f16 %0, %0, %1" : "+v"(a) : "v"(x));
}
// scalar-friendly sext-bit (compiler emits SALU for wave-uniform input)
__device__ __forceinline__ unsigned bit_sext_s(unsigned w, int off) {
    return (unsigned)(((int)(w << (31 - off))) >> 31);
}

__global__ void k_count(const int* __restrict__ src, const int* __restrict__ dst,
                        int* __restrict__ cs, int* __restrict__ cd) {
    int e = blockIdx.x * 256 + threadIdx.x;
    if (e < EE) {
        atomicAdd(&cs[src[e]], 1);
        atomicAdd(&cd[dst[e]], 1);
    }
}

__global__ void k_norm(const int* __restrict__ cs, const int* __restrict__ cd,
                       float* __restrict__ on, float* __restrict__ inn) {
    int i = blockIdx.x * 256 + threadIdx.x;
    if (i < NN) {
        int a = cs[i] > 1 ? cs[i] : 1;
        int b = cd[i] > 1 ? cd[i] : 1;
        on[i]  = 1.0f / sqrtf((float)a);
        inn[i] = 1.0f / sqrtf((float)b);
    }
}

// RB rows per block: W[k][j] read once per block for RB rows.
template<int K, int ND, int RB>
__global__ void k_gemm_scale(const float* __restrict__ X, const float* __restrict__ W,
                             const float* __restrict__ scale, float* __restrict__ out) {
    __shared__ float xr[RB][K];
    int i0 = blockIdx.x * RB;
    for (int t = threadIdx.x; t < RB * K; t += ND)
        xr[t / K][t % K] = X[(size_t)(i0 + t / K) * K + t % K];
    __syncthreads();
    int j = threadIdx.x;
    float acc[RB];
    #pragma unroll
    for (int r = 0; r < RB; ++r) acc[r] = 0.0f;
    #pragma unroll 4
    for (int k = 0; k < K; ++k) {
        float w = W[k * ND + j];
        #pragma unroll
        for (int r = 0; r < RB; ++r) acc[r] = fmaf(xr[r][k], w, acc[r]);
    }
    #pragma unroll
    for (int r = 0; r < RB; ++r)
        out[(size_t)(i0 + r) * ND + j] = acc[r] * scale[i0 + r];
}

// f32-input GEMM, RB rows/block. H16=1: relu + packed-half2 output.
template<int K, int ND, int RB, int H16>
__global__ void k_gemm_ab(const float* __restrict__ X, const float* __restrict__ W,
                          const float* __restrict__ b1, float* __restrict__ out) {
    __shared__ float xr[RB][K];
    int i0 = blockIdx.x * RB;
    for (int t = threadIdx.x; t < RB * K; t += ND)
        xr[t / K][t % K] = X[(size_t)(i0 + t / K) * K + t % K];
    __syncthreads();
    int j = threadIdx.x;
    float acc[RB];
    #pragma unroll
    for (int r = 0; r < RB; ++r) acc[r] = 0.0f;
    #pragma unroll 4
    for (int k = 0; k < K; ++k) {
        float w = W[k * ND + j];
        #pragma unroll
        for (int r = 0; r < RB; ++r) acc[r] = fmaf(xr[r][k], w, acc[r]);
    }
    if constexpr (H16) {
        unsigned* oh = (unsigned*)out;
        #pragma unroll
        for (int r = 0; r < RB; ++r) {
            float v = fmaxf(acc[r] + b1[j], 0.0f);
            float o2 = __shfl_xor(v, 1, 64);
            if ((j & 1) == 0) {
                __half2 h = __floats2half2_rn(v, o2);
                oh[(size_t)(i0 + r) * (ND / 2) + (j >> 1)] = *(unsigned*)&h;
            }
        }
    } else {
        #pragma unroll
        for (int r = 0; r < RB; ++r)
            out[(size_t)(i0 + r) * ND + j] = acc[r] + b1[j];
    }
}

// Merge GEMM from NS fp16-packed partials: X = max over splits (packed pkmax,
// lossless: partials are exact fp16 values), then f32 GEMM. L2N=1: fused
// relu + l2-normalize epilogue (same reduction order as before).
template<int K, int ND, int NS, int RB, int L2N>
__global__ void k_gemm_mrgh(const unsigned* __restrict__ Xh, size_t xstride,
                            const float* __restrict__ W,
                            const float* __restrict__ b1, const float* __restrict__ b2,
                            float* __restrict__ out) {
    __shared__ float xr[RB][K];
    int i0 = blockIdx.x * RB;
    for (int t = threadIdx.x; t < RB * (K / 2); t += ND) {
        int r = t / (K / 2), c = t % (K / 2);
        size_t off = (size_t)(i0 + r) * (K / 2) + c;
        unsigned v = Xh[off];
        #pragma unroll
        for (int s = 1; s < NS; ++s) pkmax(v, Xh[(size_t)s * xstride + off]);
        __half2 h = *(__half2*)&v;
        float2 f = __half22float2(h);
        xr[r][2 * c] = f.x;
        xr[r][2 * c + 1] = f.y;
    }
    __syncthreads();
    int j = threadIdx.x;
    float acc[RB];
    #pragma unroll
    for (int r = 0; r < RB; ++r) acc[r] = 0.0f;
    #pragma unroll 4
    for (int k = 0; k < K; ++k) {
        float w = W[k * ND + j];
        #pragma unroll
        for (int r = 0; r < RB; ++r) acc[r] = fmaf(xr[r][k], w, acc[r]);
    }
    if constexpr (L2N) {
        float v[RB], ss[RB];
        #pragma unroll
        for (int r = 0; r < RB; ++r) {
            float t = acc[r] + b1[j];
            if (b2) t += b2[j];
            v[r] = fmaxf(t, 0.0f);
            ss[r] = v[r] * v[r];
        }
        #pragma unroll
        for (int o = 1; o < 64; o <<= 1)
            #pragma unroll
            for (int r = 0; r < RB; ++r) ss[r] += __shfl_xor(ss[r], o, 64);
        __shared__ float sred[RB][2];
        if ((threadIdx.x & 63) == 0)
            #pragma unroll
            for (int r = 0; r < RB; ++r) sred[r][threadIdx.x >> 6] = ss[r];
        __syncthreads();
        #pragma unroll
        for (int r = 0; r < RB; ++r) {
            float tot = sred[r][0] + sred[r][1];
            out[(size_t)(i0 + r) * ND + j] = v[r] / fmaxf(sqrtf(tot), 1e-12f);
        }
    } else {
        #pragma unroll
        for (int r = 0; r < RB; ++r) {
            float v = acc[r] + b1[j];
            if (b2) v += b2[j];
            out[(size_t)(i0 + r) * ND + j] = v;
        }
    }
}

// Batched edge scatter: 16 edges/block, 4 waves (wave per edge round-robin),
// lane covers 2 dims via float2 loads. Atomic count unchanged.
__global__ void k_scatter(const float* __restrict__ t, const int* __restrict__ src,
                          const int* __restrict__ dst, float* __restrict__ agg) {
    int wave = threadIdx.x >> 6;
    int lane = threadIdx.x & 63;
    int base = blockIdx.x * 16;
    for (int ee = wave; ee < 16; ee += 4) {
        int e = base + ee;
        int s = src[e], d = dst[e];
        float2 v = *(const float2*)(t + (size_t)s * 128 + 2 * lane);
        atomicAdd(&agg[(size_t)d * 128 + 2 * lane], v.x);
        atomicAdd(&agg[(size_t)d * 128 + 2 * lane + 1], v.y);
    }
}

__global__ void k_gcn_out(const float* __restrict__ agg, const float* __restrict__ inn,
                          const float* __restrict__ b, float* __restrict__ out, int do_relu) {
    int idx = blockIdx.x * 256 + threadIdx.x;
    int i = idx >> 7, j = idx & 127;
    float v = agg[idx] * inn[i] + b[j];
    if (do_relu) v = fmaxf(v, 0.0f);
    out[idx] = v;
}

// ---- S = h h^T 64x64 tile; MODE 0: max-only; MODE 1: recompute + bit-emit ----
template<int MODE>
__global__ __launch_bounds__(256, 4) void k_stile(const float* __restrict__ h,
                                                  const float* __restrict__ u,
                                                  unsigned* __restrict__ smax_key,
                                                  unsigned* __restrict__ mb) {
    int ti = blockIdx.y, tj = blockIdx.x;
    if (tj < ti) return;
    __shared__ float Ah[TS][68];
    __shared__ float Bh[TS][68];
    int tid = threadIdx.x;
    int tx = tid & 15, ty = tid >> 4;
    const float* ha = h + (size_t)ti * TS * 128;
    const float* hb = h + (size_t)tj * TS * 128;

    float acc[4][4];
    #pragma unroll
    for (int r = 0; r < 4; ++r)
        #pragma unroll
        for (int c = 0; c < 4; ++c) acc[r][c] = 0.0f;

    for (int half = 0; half < 2; ++half) {
        __syncthreads();
        #pragma unroll
        for (int t = 0; t < 4; ++t) {
            int f = tid + t * 256;
            int row = f >> 4, kk = f & 15;
            *(float4*)&Ah[row][kk * 4] = *(const float4*)(ha + (size_t)row * 128 + half * 64 + kk * 4);
            *(float4*)&Bh[row][kk * 4] = *(const float4*)(hb + (size_t)row * 128 + half * 64 + kk * 4);
        }
        __syncthreads();
        #pragma unroll 2
        for (int k4 = 0; k4 < 16; ++k4) {
            float4 a[4], b[4];
            #pragma unroll
            for (int r = 0; r < 4; ++r) a[r] = *(const float4*)&Ah[ty + 16 * r][k4 * 4];
            #pragma unroll
            for (int c = 0; c < 4; ++c) b[c] = *(const float4*)&Bh[tx + 16 * c][k4 * 4];
            #pragma unroll
            for (int r = 0; r < 4; ++r)
                #pragma unroll
                for (int c = 0; c < 4; ++c) {
                    acc[r][c] = fmaf(a[r].x, b[c].x, acc[r][c]);
                    acc[r][c] = fmaf(a[r].y, b[c].y, acc[r][c]);
                    acc[r][c] = fmaf(a[r].z, b[c].z, acc[r][c]);
                    acc[r][c] = fmaf(a[r].w, b[c].w, acc[r][c]);
                }
        }
    }

    if constexpr (MODE == 0) {
        float m = -3.4e38f;
        #pragma unroll
        for (int r = 0; r < 4; ++r)
            #pragma unroll
            for (int c = 0; c < 4; ++c) m = fmaxf(m, acc[r][c]);
        #pragma unroll
        for (int o = 1; o < 64; o <<= 1) m = fmaxf(m, __shfl_xor(m, o, 64));
        __shared__ float wm[4];
        if ((tid & 63) == 0) wm[tid >> 6] = m;
        __syncthreads();
        if (tid == 0) {
            float mm = fmaxf(fmaxf(wm[0], wm[1]), fmaxf(wm[2], wm[3]));
            atomicMax(smax_key, fkey(mm));
        }
    } else {
        float smax = funkey(*smax_key);
        float epmax = 1.0f / (1.0f + expf(-smax));
        __shared__ unsigned lm[TS][2];
        __shared__ unsigned lmT[TS][2];
        if (tid < 128) { lm[tid >> 1][tid & 1] = 0u; lmT[tid >> 1][tid & 1] = 0u; }
        __syncthreads();
        #pragma unroll
        for (int r = 0; r < 4; ++r) {
            #pragma unroll
            for (int c = 0; c < 4; ++c) {
                int li = ty + 16 * r, lj = tx + 16 * c;
                int gi = ti * TS + li, gj = tj * TS + lj;
                bool bit = false;
                if (gi < gj) {
                    float ep = 1.0f / (1.0f + expf(-acc[r][c]));
                    float P = ep / epmax;
                    float Pc = fminf(fmaxf(P, 1e-6f), 1.0f - 1e-6f);
                    float uu = u[(size_t)gi * NN + gj];
                    float ucv = fminf(fmaxf(uu, 1e-6f), 1.0f - 1e-6f);
                    bit = Pc > (1.0f - ucv);
                } else if (gi == gj) {
                    bit = true;
                }
                if (bit) {
                    atomicOr(&lm[li][lj >> 5], 1u << (lj & 31));
                    atomicOr(&lmT[lj][li >> 5], 1u << (li & 31));
                }
            }
        }
        __syncthreads();
        if (tid < 128) {
            int r = tid >> 1, wq = tid & 1;
            unsigned word = lm[r][wq];
            if (ti == tj) word |= lmT[r][wq];
            mb[(size_t)(ti * TS + r) * 128 + tj * 2 + wq] = word;
        } else if (ti != tj) {
            int r = (tid - 128) >> 1, wq = tid & 1;
            mb[(size_t)(tj * TS + r) * 128 + ti * 2 + wq] = lmT[r][wq];
        }
    }
}

// Pass 1 (S-store path): compute tile, store S to ws, fold into global max.
__global__ __launch_bounds__(256, 4) void k_stile_store(const float* __restrict__ h,
                                                        float* __restrict__ S,
                                                        unsigned* __restrict__ smax_key) {
    int ti = blockIdx.y, tj = blockIdx.x;
    if (tj < ti) return;
    __shared__ float Ah[TS][68];
    __shared__ float Bh[TS][68];
    int tid = threadIdx.x;
    int tx = tid & 15, ty = tid >> 4;
    const float* ha = h + (size_t)ti * TS * 128;
    const float* hb = h + (size_t)tj * TS * 128;

    float acc[4][4];
    #pragma unroll
    for (int r = 0; r < 4; ++r)
        #pragma unroll
        for (int c = 0; c < 4; ++c) acc[r][c] = 0.0f;

    for (int half = 0; half < 2; ++half) {
        __syncthreads();
        #pragma unroll
        for (int t = 0; t < 4; ++t) {
            int f = tid + t * 256;
            int row = f >> 4, kk = f & 15;
            *(float4*)&Ah[row][kk * 4] = *(const float4*)(ha + (size_t)row * 128 + half * 64 + kk * 4);
            *(float4*)&Bh[row][kk * 4] = *(const float4*)(hb + (size_t)row * 128 + half * 64 + kk * 4);
        }
        __syncthreads();
        #pragma unroll 2
        for (int k4 = 0; k4 < 16; ++k4) {
            float4 a[4], b[4];
            #pragma unroll
            for (int r = 0; r < 4; ++r) a[r] = *(const float4*)&Ah[ty + 16 * r][k4 * 4];
            #pragma unroll
            for (int c = 0; c < 4; ++c) b[c] = *(const float4*)&Bh[tx + 16 * c][k4 * 4];
            #pragma unroll
            for (int r = 0; r < 4; ++r)
                #pragma unroll
                for (int c = 0; c < 4; ++c) {
                    acc[r][c] = fmaf(a[r].x, b[c].x, acc[r][c]);
                    acc[r][c] = fmaf(a[r].y, b[c].y, acc[r][c]);
                    acc[r][c] = fmaf(a[r].z, b[c].z, acc[r][c]);
                    acc[r][c] = fmaf(a[r].w, b[c].w, acc[r][c]);
                }
        }
    }

    float* sp = S + (size_t)(ti * 64 + tj) * 4096;
    #pragma unroll
    for (int r = 0; r < 4; ++r)
        #pragma unroll
        for (int c = 0; c < 4; ++c)
            sp[(ty + 16 * r) * 64 + tx + 16 * c] = acc[r][c];

    float m = -3.4e38f;
    #pragma unroll
    for (int r = 0; r < 4; ++r)
        #pragma unroll
        for (int c = 0; c < 4; ++c) m = fmaxf(m, acc[r][c]);
    #pragma unroll
    for (int o = 1; o < 64; o <<= 1) m = fmaxf(m, __shfl_xor(m, o, 64));
    __shared__ float wm[4];
    if ((tid & 63) == 0) wm[tid >> 6] = m;
    __syncthreads();
    if (tid == 0)
        atomicMax(smax_key, fkey(fmaxf(fmaxf(wm[0], wm[1]), fmaxf(wm[2], wm[3]))));
}

// Pass 2 (S-store path): read stored S, emit mask bits.
__global__ __launch_bounds__(256, 4) void k_bitemit(const float* __restrict__ S,
                                                    const float* __restrict__ u,
                                                    const unsigned* __restrict__ smax_key,
                                                    unsigned* __restrict__ mb) {
    int ti = blockIdx.y, tj = blockIdx.x;
    if (tj < ti) return;
    int tid = threadIdx.x;
    int tx = tid & 15, ty = tid >> 4;
    float smax = funkey(*smax_key);
    float epmax = 1.0f / (1.0f + expf(-smax));
    __shared__ unsigned lm[TS][2];
    __shared__ unsigned lmT[TS][2];
    if (tid < 128) { lm[tid >> 1][tid & 1] = 0u; lmT[tid >> 1][tid & 1] = 0u; }
    __syncthreads();
    const float* sp = S + (size_t)(ti * 64 + tj) * 4096;
    #pragma unroll
    for (int r = 0; r < 4; ++r) {
        #pragma unroll
        for (int c = 0; c < 4; ++c) {
            int li = ty + 16 * r, lj = tx + 16 * c;
            int gi = ti * TS + li, gj = tj * TS + lj;
            bool bit = false;
            if (gi < gj) {
                float ep = 1.0f / (1.0f + expf(-sp[li * 64 + lj]));
                float P = ep / epmax;
                float Pc = fminf(fmaxf(P, 1e-6f), 1.0f - 1e-6f);
                float uu = u[(size_t)gi * NN + gj];
                float ucv = fminf(fmaxf(uu, 1e-6f), 1.0f - 1e-6f);
                bit = Pc > (1.0f - ucv);
            } else if (gi == gj) {
                bit = true;
            }
            if (bit) {
                atomicOr(&lm[li][lj >> 5], 1u << (lj & 31));
                atomicOr(&lmT[lj][li >> 5], 1u << (li & 31));
            }
        }
    }
    __syncthreads();
    if (tid < 128) {
        int r = tid >> 1, wq = tid & 1;
        unsigned word = lm[r][wq];
        if (ti == tj) word |= lmT[r][wq];
        mb[(size_t)(ti * TS + r) * 128 + tj * 2 + wq] = word;
    } else if (ti != tj) {
        int r = (tid - 128) >> 1, wq = tid & 1;
        mb[(size_t)(tj * TS + r) * 128 + ti * 2 + wq] = lmT[r][wq];
    }
}

// Masked max, D=256, fp16-packed z; fp16-packed partial output (lossless).
template<int RT, int JS>
__global__ __launch_bounds__(256, 8) void k_mmax256h(const unsigned* __restrict__ mb,
                                                     const unsigned* __restrict__ zh,
                                                     unsigned* __restrict__ pmh) {
    constexpr int JPS = NN / JS;   // 512
    constexpr int WPS = JPS / 32;  // 16
    constexpr int RPG = RT / 4;    // 4
    constexpr int NRB = NN / RT;   // 256
    int rowblk = blockIdx.x % NRB, js = blockIdx.x / NRB;
    int i0 = rowblk * RT;

    __shared__ unsigned msk[RT][WPS + 1];
    {
        int t = threadIdx.x;           // RT*WPS == 256
        msk[t / WPS][t % WPS] = mb[(size_t)(i0 + t / WPS) * 128 + js * WPS + t % WPS];
    }
    __syncthreads();

    int d = threadIdx.x & 63;
    int g = threadIdx.x >> 6;
    const uint2* zbase = (const uint2*)zh + (size_t)js * JPS * 64 + d;   // row = 64 uint2

    uint2 acc[RPG];
    #pragma unroll
    for (int r = 0; r < RPG; ++r) acc[r] = make_uint2(0u, 0u);

    #pragma unroll 1
    for (int wq = 0; wq < WPS; ++wq) {
        unsigned m[RPG];
        #pragma unroll
        for (int r = 0; r < RPG; ++r)
            m[r] = (unsigned)__builtin_amdgcn_readfirstlane((int)msk[g * RPG + r][wq]);
        const uint2* zp = zbase + (size_t)(wq * 32) * 64;
        #pragma unroll 2
        for (int j4 = 0; j4 < 32; j4 += 4) {
            uint2 z0 = zp[0 * 64];
            uint2 z1 = zp[1 * 64];
            uint2 z2 = zp[2 * 64];
            uint2 z3 = zp[3 * 64];
            #pragma unroll
            for (int r = 0; r < RPG; ++r) {
                unsigned s0 = bit_sext_s(m[r], j4 + 0);
                unsigned s1 = bit_sext_s(m[r], j4 + 1);
                unsigned s2 = bit_sext_s(m[r], j4 + 2);
                unsigned s3 = bit_sext_s(m[r], j4 + 3);
                pkmax(acc[r].x, s0 & z0.x); pkmax(acc[r].y, s0 & z0.y);
                pkmax(acc[r].x, s1 & z1.x); pkmax(acc[r].y, s1 & z1.y);
                pkmax(acc[r].x, s2 & z2.x); pkmax(acc[r].y, s2 & z2.y);
                pkmax(acc[r].x, s3 & z3.x); pkmax(acc[r].y, s3 & z3.y);
            }
            zp += 4 * 64;
        }
    }

    uint2* po = (uint2*)(pmh + (size_t)js * NN * 128);   // row = 128 u32 = 64 uint2
    #pragma unroll
    for (int r = 0; r < RPG; ++r)
        po[(size_t)(i0 + g * RPG + r) * 64 + d] = acc[r];
}

// Masked max, D=128, fp16-packed z; fp16-packed partial output.
template<int RT, int JS>
__global__ __launch_bounds__(256, 8) void k_mmax128h(const unsigned* __restrict__ mb,
                                                     const unsigned* __restrict__ zh,
                                                     unsigned* __restrict__ pmh) {
    constexpr int JPS = NN / JS;   // 512
    constexpr int WPS = JPS / 32;  // 16
    constexpr int RPG = RT / 4;    // 4
    constexpr int NRB = NN / RT;   // 256
    int rowblk = blockIdx.x % NRB, js = blockIdx.x / NRB;
    int i0 = rowblk * RT;

    __shared__ unsigned msk[RT][WPS + 1];
    {
        int t = threadIdx.x;
        msk[t / WPS][t % WPS] = mb[(size_t)(i0 + t / WPS) * 128 + js * WPS + t % WPS];
    }
    __syncthreads();

    int lane = threadIdx.x & 63;
    int g = threadIdx.x >> 6;
    unsigned jpar = lane >> 5;
    int d2 = lane & 31;                 // uint2 index within row (32 uint2 = 64 u32)
    const uint2* zbase = (const uint2*)zh + (size_t)js * JPS * 32 + d2;

    uint2 acc[RPG];
    #pragma unroll
    for (int r = 0; r < RPG; ++r) acc[r] = make_uint2(0u, 0u);

    #pragma unroll 1
    for (int wq = 0; wq < WPS; ++wq) {
        unsigned m[RPG];
        #pragma unroll
        for (int r = 0; r < RPG; ++r)
            m[r] = (unsigned)__builtin_amdgcn_readfirstlane((int)msk[g * RPG + r][wq]);
        const uint2* zp = zbase + (size_t)(wq * 32) * 32;
        #pragma unroll 2
        for (int j4 = 0; j4 < 32; j4 += 4) {
            uint2 za = zp[(size_t)jpar * 32];
            uint2 zb = zp[(size_t)(2 + jpar) * 32];
            int oa = j4 + (int)jpar, ob = j4 + 2 + (int)jpar;
            #pragma unroll
            for (int r = 0; r < RPG; ++r) {
                unsigned sa = bit_sext_s(m[r], oa);
                unsigned sb = bit_sext_s(m[r], ob);
                pkmax(acc[r].x, sa & za.x); pkmax(acc[r].y, sa & za.y);
                pkmax(acc[r].x, sb & zb.x); pkmax(acc[r].y, sb & zb.y);
            }
            zp += 4 * 32;
        }
    }

    #pragma unroll
    for (int r = 0; r < RPG; ++r) {
        unsigned ox = __shfl_xor(acc[r].x, 32, 64);
        unsigned oy = __shfl_xor(acc[r].y, 32, 64);
        pkmax(acc[r].x, ox);
        pkmax(acc[r].y, oy);
    }
    if (!jpar) {
        uint2* po = (uint2*)(pmh + (size_t)js * NN * 64);   // row = 64 u32 = 32 uint2
        #pragma unroll
        for (int r = 0; r < RPG; ++r)
            po[(size_t)(i0 + g * RPG + r) * 32 + d2] = acc[r];
    }
}

// Final 128->32 GEMM, NS fp16-packed partials, LDS-staged, 4 rows per block.
template<int NS>
__global__ void k_gemm_final(const unsigned* __restrict__ Xh, size_t xstride,
                             const float* __restrict__ W,
                             const float* __restrict__ b1, const float* __restrict__ b2,
                             float* __restrict__ out) {
    __shared__ float xr[4][128];
    int i0 = blockIdx.x * 4;
    for (int t = threadIdx.x; t < 256; t += 128) {
        int r = t >> 6, c = t & 63;
        size_t off = (size_t)(i0 + r) * 64 + c;
        unsigned v = Xh[off];
        #pragma unroll
        for (int s = 1; s < NS; ++s) pkmax(v, Xh[(size_t)s * xstride + off]);
        __half2 h = *(__half2*)&v;
        float2 f = __half22float2(h);
        xr[r][2 * c] = f.x;
        xr[r][2 * c + 1] = f.y;
    }
    __syncthreads();
    int il = threadIdx.x >> 5, j = threadIdx.x & 31;
    float acc = 0.0f;
    #pragma unroll 8
    for (int k = 0; k < 128; ++k) acc = fmaf(xr[il][k], W[k * 32 + j], acc);
    out[(size_t)(i0 + il) * 32 + j] = acc + b1[j] + b2[j];
}

extern "C" void kernel_launch(void* const* d_in, const int* in_sizes, int n_in,
                              void* d_out, int out_size, void* d_ws, size_t ws_size,
                              hipStream_t stream) {
    const float* inputs = (const float*)d_in[1];
    const float* feat   = (const float*)d_in[2];
    const float* u      = (const float*)d_in[3];
    const int*   src    = (const int*)d_in[4];
    const int*   dst    = (const int*)d_in[5];
    const float* gc0W = (const float*)d_in[6],  *gc0b = (const float*)d_in[7];
    const float* gc1W = (const float*)d_in[8],  *gc1b = (const float*)d_in[9];
    const float* p0W  = (const float*)d_in[10], *p0b  = (const float*)d_in[11];
    const float* l0W  = (const float*)d_in[12], *l0b  = (const float*)d_in[13];
    const float* b0   = (const float*)d_in[14];
    const float* p1W  = (const float*)d_in[15], *p1b  = (const float*)d_in[16];
    const float* l1W  = (const float*)d_in[17], *l1b  = (const float*)d_in[18];
    const float* b1   = (const float*)d_in[19];
    const float* p2W  = (const float*)d_in[20], *p2b  = (const float*)d_in[21];
    const float* l2W  = (const float*)d_in[22], *l2b  = (const float*)d_in[23];
    const float* b2   = (const float*)d_in[24];
    float* out = (float*)d_out;

    const size_t MB = 1048576;
    char* w = (char*)d_ws;
    int*      cnt_src  = (int*)(w + 0);            // 16 KB
    int*      cnt_dst  = (int*)(w + 16384);        // 16 KB
    float*    on       = (float*)(w + 32768);      // 16 KB
    float*    inn      = (float*)(w + 49152);      // 16 KB
    unsigned* smax_key = (unsigned*)(w + 65536);   // pad to 128 KB
    char*     big      = w + 131072;
    float*    tmp      = (float*)(big);            // 2 MB
    float*    agg      = (float*)(big + 2 * MB);   // 2 MB
    float*    hbuf     = (float*)(big + 4 * MB);   // 2 MB
    unsigned* mb       = (unsigned*)(big + 6 * MB);// 2 MB
    unsigned* zh       = (unsigned*)(big + 8 * MB);// 2 MB (fp16-packed z)
    unsigned* pmh      = (unsigned*)(big + 12 * MB);// 16 MB (8 fp16 split partials)
    float*    hs       = (float*)(big + 44 * MB);  // 2 MB
    float*    Sbuf     = (float*)(big + 46 * MB);  // 64 MB
    bool use_sstore = ws_size >= 131072 + 110 * MB;

    hipMemsetAsync(w, 0, 131072, stream);
    k_count<<<EE / 256, 256, 0, stream>>>(src, dst, cnt_src, cnt_dst);
    k_norm<<<NN / 256, 256, 0, stream>>>(cnt_src, cnt_dst, on, inn);

    // --- GCN layer 0 ---
    k_gemm_scale<256, 128, 4><<<NN / 4, 128, 0, stream>>>(inputs, gc0W, on, tmp);
    hipMemsetAsync(agg, 0, (size_t)NN * 128 * 4, stream);
    k_scatter<<<EE / 16, 256, 0, stream>>>(tmp, src, dst, agg);
    k_gcn_out<<<NN * 128 / 256, 256, 0, stream>>>(agg, inn, gc0b, hbuf, 1);

    // --- GCN layer 1 ---
    k_gemm_scale<128, 128, 4><<<NN / 4, 128, 0, stream>>>(hbuf, gc1W, on, tmp);
    hipMemsetAsync(agg, 0, (size_t)NN * 128 * 4, stream);
    k_scatter<<<EE / 16, 256, 0, stream>>>(tmp, src, dst, agg);
    k_gcn_out<<<NN * 128 / 256, 256, 0, stream>>>(agg, inn, gc1b, hbuf, 0);

    // --- decode: S max + mask bits ---
    dim3 tg(64, 64);
    if (use_sstore) {
        k_stile_store<<<tg, 256, 0, stream>>>(hbuf, Sbuf, smax_key);
        k_bitemit<<<tg, 256, 0, stream>>>(Sbuf, u, smax_key, mb);
    } else {
        k_stile<0><<<tg, 256, 0, stream>>>(hbuf, nullptr, smax_key, nullptr);
        k_stile<1><<<tg, 256, 0, stream>>>(hbuf, u, smax_key, mb);
    }

    // --- GraphSAGE layer 0 (256 -> 128), fp16 masked max + fp16 partials ---
    k_gemm_ab<256, 256, 4, 1><<<NN / 4, 256, 0, stream>>>(feat, p0W, p0b, (float*)zh);
    k_mmax256h<16, 8><<<(NN / 16) * 8, 256, 0, stream>>>(mb, zh, pmh);
    k_gemm_mrgh<256, 128, 8, 4, 1><<<NN / 4, 128, 0, stream>>>(pmh, (size_t)NN * 128, l0W, l0b, b0, hs);

    // --- GraphSAGE layer 1 (128 -> 128) ---
    k_gemm_ab<128, 128, 4, 1><<<NN / 4, 128, 0, stream>>>(hs, p1W, p1b, (float*)zh);
    k_mmax128h<16, 8><<<(NN / 16) * 8, 256, 0, stream>>>(mb, zh, pmh);
    k_gemm_mrgh<128, 128, 8, 4, 1><<<NN / 4, 128, 0, stream>>>(pmh, (size_t)NN * 64, l1W, l1b, b1, tmp);

    // --- GraphSAGE layer 2 (128 -> 32) ---
    k_gemm_ab<128, 128, 4, 1><<<NN / 4, 128, 0, stream>>>(tmp, p2W, p2b, (float*)zh);
    k_mmax128h<16, 8><<<(NN / 16) * 8, 256, 0, stream>>>(mb, zh, pmh);
    k_gemm_final<8><<<NN / 4, 128, 0, stream>>>(pmh, (size_t)NN * 64, l2W, l2b, b2, out);
}

// Round 18
// 670.261 us; speedup vs baseline: 1.1605x; 1.1605x over previous
//
#include <hip/hip_runtime.h>
#include <hip/hip_fp16.h>
#include <cstdint>
#include <cstddef>

#define NN 4096
#define EE 131072
#define TS 64

__device__ __forceinline__ unsigned fkey(float f) {
    unsigned u = __float_as_uint(f);
    return (u & 0x80000000u) ? ~u : (u | 0x80000000u);
}
__device__ __forceinline__ float funkey(unsigned k) {
    unsigned u = (k & 0x80000000u) ? (k & 0x7fffffffu) : ~k;
    return __uint_as_float(u);
}

// ---- VALU-only asm pins (no SALU/SCC writes; proven safe rounds 14-17) ----
__device__ __forceinline__ void pkmax(unsigned& a, unsigned x) {
    asm("v_pk_max_f16 %0, %0, %1" : "+v"(a) : "v"(x));
}
// scalar-friendly sext-bit (compiler emits SALU for wave-uniform input)
__device__ __forceinline__ unsigned bit_sext_s(unsigned w, int off) {
    return (unsigned)(((int)(w << (31 - off))) >> 31);
}

__global__ void k_count(const int* __restrict__ src, const int* __restrict__ dst,
                        int* __restrict__ cs, int* __restrict__ cd) {
    int e = blockIdx.x * 256 + threadIdx.x;
    if (e < EE) {
        atomicAdd(&cs[src[e]], 1);
        atomicAdd(&cd[dst[e]], 1);
    }
}

__global__ void k_norm(const int* __restrict__ cs, const int* __restrict__ cd,
                       float* __restrict__ on, float* __restrict__ inn) {
    int i = blockIdx.x * 256 + threadIdx.x;
    if (i < NN) {
        int a = cs[i] > 1 ? cs[i] : 1;
        int b = cd[i] > 1 ? cd[i] : 1;
        on[i]  = 1.0f / sqrtf((float)a);
        inn[i] = 1.0f / sqrtf((float)b);
    }
}

// RB rows per block: W[k][j] read once per block for RB rows.
template<int K, int ND, int RB>
__global__ void k_gemm_scale(const float* __restrict__ X, const float* __restrict__ W,
                             const float* __restrict__ scale, float* __restrict__ out) {
    __shared__ float xr[RB][K];
    int i0 = blockIdx.x * RB;
    for (int t = threadIdx.x; t < RB * K; t += ND)
        xr[t / K][t % K] = X[(size_t)(i0 + t / K) * K + t % K];
    __syncthreads();
    int j = threadIdx.x;
    float acc[RB];
    #pragma unroll
    for (int r = 0; r < RB; ++r) acc[r] = 0.0f;
    #pragma unroll 4
    for (int k = 0; k < K; ++k) {
        float w = W[k * ND + j];
        #pragma unroll
        for (int r = 0; r < RB; ++r) acc[r] = fmaf(xr[r][k], w, acc[r]);
    }
    #pragma unroll
    for (int r = 0; r < RB; ++r)
        out[(size_t)(i0 + r) * ND + j] = acc[r] * scale[i0 + r];
}

// f32-input GEMM, RB rows/block. H16=1: relu + packed-half2 output.
template<int K, int ND, int RB, int H16>
__global__ void k_gemm_ab(const float* __restrict__ X, const float* __restrict__ W,
                          const float* __restrict__ b1, float* __restrict__ out) {
    __shared__ float xr[RB][K];
    int i0 = blockIdx.x * RB;
    for (int t = threadIdx.x; t < RB * K; t += ND)
        xr[t / K][t % K] = X[(size_t)(i0 + t / K) * K + t % K];
    __syncthreads();
    int j = threadIdx.x;
    float acc[RB];
    #pragma unroll
    for (int r = 0; r < RB; ++r) acc[r] = 0.0f;
    #pragma unroll 4
    for (int k = 0; k < K; ++k) {
        float w = W[k * ND + j];
        #pragma unroll
        for (int r = 0; r < RB; ++r) acc[r] = fmaf(xr[r][k], w, acc[r]);
    }
    if constexpr (H16) {
        unsigned* oh = (unsigned*)out;
        #pragma unroll
        for (int r = 0; r < RB; ++r) {
            float v = fmaxf(acc[r] + b1[j], 0.0f);
            float o2 = __shfl_xor(v, 1, 64);
            if ((j & 1) == 0) {
                __half2 h = __floats2half2_rn(v, o2);
                oh[(size_t)(i0 + r) * (ND / 2) + (j >> 1)] = *(unsigned*)&h;
            }
        }
    } else {
        #pragma unroll
        for (int r = 0; r < RB; ++r)
            out[(size_t)(i0 + r) * ND + j] = acc[r] + b1[j];
    }
}

// Merge GEMM from NS fp16-packed partials (packed pkmax merge, lossless),
// then f32 GEMM. L2N=1: fused relu + l2-normalize epilogue.
template<int K, int ND, int NS, int RB, int L2N>
__global__ void k_gemm_mrgh(const unsigned* __restrict__ Xh, size_t xstride,
                            const float* __restrict__ W,
                            const float* __restrict__ b1, const float* __restrict__ b2,
                            float* __restrict__ out) {
    __shared__ float xr[RB][K];
    int i0 = blockIdx.x * RB;
    for (int t = threadIdx.x; t < RB * (K / 2); t += ND) {
        int r = t / (K / 2), c = t % (K / 2);
        size_t off = (size_t)(i0 + r) * (K / 2) + c;
        unsigned v = Xh[off];
        #pragma unroll
        for (int s = 1; s < NS; ++s) pkmax(v, Xh[(size_t)s * xstride + off]);
        __half2 h = *(__half2*)&v;
        float2 f = __half22float2(h);
        xr[r][2 * c] = f.x;
        xr[r][2 * c + 1] = f.y;
    }
    __syncthreads();
    int j = threadIdx.x;
    float acc[RB];
    #pragma unroll
    for (int r = 0; r < RB; ++r) acc[r] = 0.0f;
    #pragma unroll 4
    for (int k = 0; k < K; ++k) {
        float w = W[k * ND + j];
        #pragma unroll
        for (int r = 0; r < RB; ++r) acc[r] = fmaf(xr[r][k], w, acc[r]);
    }
    if constexpr (L2N) {
        float v[RB], ss[RB];
        #pragma unroll
        for (int r = 0; r < RB; ++r) {
            float t = acc[r] + b1[j];
            if (b2) t += b2[j];
            v[r] = fmaxf(t, 0.0f);
            ss[r] = v[r] * v[r];
        }
        #pragma unroll
        for (int o = 1; o < 64; o <<= 1)
            #pragma unroll
            for (int r = 0; r < RB; ++r) ss[r] += __shfl_xor(ss[r], o, 64);
        __shared__ float sred[RB][2];
        if ((threadIdx.x & 63) == 0)
            #pragma unroll
            for (int r = 0; r < RB; ++r) sred[r][threadIdx.x >> 6] = ss[r];
        __syncthreads();
        #pragma unroll
        for (int r = 0; r < RB; ++r) {
            float tot = sred[r][0] + sred[r][1];
            out[(size_t)(i0 + r) * ND + j] = v[r] / fmaxf(sqrtf(tot), 1e-12f);
        }
    } else {
        #pragma unroll
        for (int r = 0; r < RB; ++r) {
            float v = acc[r] + b1[j];
            if (b2) v += b2[j];
            out[(size_t)(i0 + r) * ND + j] = v;
        }
    }
}

// Per-edge-block scatter (proven form: 1 block/edge, 128 threads, 1 atomic each).
__global__ void k_scatter(const float* __restrict__ t, const int* __restrict__ src,
                          const int* __restrict__ dst, float* __restrict__ agg) {
    int e = blockIdx.x;
    int j = threadIdx.x;   // 128 threads
    int s = src[e], d = dst[e];
    atomicAdd(&agg[(size_t)d * 128 + j], t[(size_t)s * 128 + j]);
}

__global__ void k_gcn_out(const float* __restrict__ agg, const float* __restrict__ inn,
                          const float* __restrict__ b, float* __restrict__ out, int do_relu) {
    int idx = blockIdx.x * 256 + threadIdx.x;
    int i = idx >> 7, j = idx & 127;
    float v = agg[idx] * inn[i] + b[j];
    if (do_relu) v = fmaxf(v, 0.0f);
    out[idx] = v;
}

// ---- S = h h^T 64x64 tile; MODE 0: max-only; MODE 1: recompute + bit-emit ----
template<int MODE>
__global__ __launch_bounds__(256, 4) void k_stile(const float* __restrict__ h,
                                                  const float* __restrict__ u,
                                                  unsigned* __restrict__ smax_key,
                                                  unsigned* __restrict__ mb) {
    int ti = blockIdx.y, tj = blockIdx.x;
    if (tj < ti) return;
    __shared__ float Ah[TS][68];
    __shared__ float Bh[TS][68];
    int tid = threadIdx.x;
    int tx = tid & 15, ty = tid >> 4;
    const float* ha = h + (size_t)ti * TS * 128;
    const float* hb = h + (size_t)tj * TS * 128;

    float acc[4][4];
    #pragma unroll
    for (int r = 0; r < 4; ++r)
        #pragma unroll
        for (int c = 0; c < 4; ++c) acc[r][c] = 0.0f;

    for (int half = 0; half < 2; ++half) {
        __syncthreads();
        #pragma unroll
        for (int t = 0; t < 4; ++t) {
            int f = tid + t * 256;
            int row = f >> 4, kk = f & 15;
            *(float4*)&Ah[row][kk * 4] = *(const float4*)(ha + (size_t)row * 128 + half * 64 + kk * 4);
            *(float4*)&Bh[row][kk * 4] = *(const float4*)(hb + (size_t)row * 128 + half * 64 + kk * 4);
        }
        __syncthreads();
        #pragma unroll 2
        for (int k4 = 0; k4 < 16; ++k4) {
            float4 a[4], b[4];
            #pragma unroll
            for (int r = 0; r < 4; ++r) a[r] = *(const float4*)&Ah[ty + 16 * r][k4 * 4];
            #pragma unroll
            for (int c = 0; c < 4; ++c) b[c] = *(const float4*)&Bh[tx + 16 * c][k4 * 4];
            #pragma unroll
            for (int r = 0; r < 4; ++r)
                #pragma unroll
                for (int c = 0; c < 4; ++c) {
                    acc[r][c] = fmaf(a[r].x, b[c].x, acc[r][c]);
                    acc[r][c] = fmaf(a[r].y, b[c].y, acc[r][c]);
                    acc[r][c] = fmaf(a[r].z, b[c].z, acc[r][c]);
                    acc[r][c] = fmaf(a[r].w, b[c].w, acc[r][c]);
                }
        }
    }

    if constexpr (MODE == 0) {
        float m = -3.4e38f;
        #pragma unroll
        for (int r = 0; r < 4; ++r)
            #pragma unroll
            for (int c = 0; c < 4; ++c) m = fmaxf(m, acc[r][c]);
        #pragma unroll
        for (int o = 1; o < 64; o <<= 1) m = fmaxf(m, __shfl_xor(m, o, 64));
        __shared__ float wm[4];
        if ((tid & 63) == 0) wm[tid >> 6] = m;
        __syncthreads();
        if (tid == 0) {
            float mm = fmaxf(fmaxf(wm[0], wm[1]), fmaxf(wm[2], wm[3]));
            atomicMax(smax_key, fkey(mm));
        }
    } else {
        float smax = funkey(*smax_key);
        float epmax = 1.0f / (1.0f + expf(-smax));
        __shared__ unsigned lm[TS][2];
        __shared__ unsigned lmT[TS][2];
        if (tid < 128) { lm[tid >> 1][tid & 1] = 0u; lmT[tid >> 1][tid & 1] = 0u; }
        __syncthreads();
        #pragma unroll
        for (int r = 0; r < 4; ++r) {
            #pragma unroll
            for (int c = 0; c < 4; ++c) {
                int li = ty + 16 * r, lj = tx + 16 * c;
                int gi = ti * TS + li, gj = tj * TS + lj;
                bool bit = false;
                if (gi < gj) {
                    float ep = 1.0f / (1.0f + expf(-acc[r][c]));
                    float P = ep / epmax;
                    float Pc = fminf(fmaxf(P, 1e-6f), 1.0f - 1e-6f);
                    float uu = u[(size_t)gi * NN + gj];
                    float ucv = fminf(fmaxf(uu, 1e-6f), 1.0f - 1e-6f);
                    bit = Pc > (1.0f - ucv);
                } else if (gi == gj) {
                    bit = true;
                }
                if (bit) {
                    atomicOr(&lm[li][lj >> 5], 1u << (lj & 31));
                    atomicOr(&lmT[lj][li >> 5], 1u << (li & 31));
                }
            }
        }
        __syncthreads();
        if (tid < 128) {
            int r = tid >> 1, wq = tid & 1;
            unsigned word = lm[r][wq];
            if (ti == tj) word |= lmT[r][wq];
            mb[(size_t)(ti * TS + r) * 128 + tj * 2 + wq] = word;
        } else if (ti != tj) {
            int r = (tid - 128) >> 1, wq = tid & 1;
            mb[(size_t)(tj * TS + r) * 128 + ti * 2 + wq] = lmT[r][wq];
        }
    }
}

// Pass 1 (S-store path): compute tile, store S to ws, fold into global max.
__global__ __launch_bounds__(256, 4) void k_stile_store(const float* __restrict__ h,
                                                        float* __restrict__ S,
                                                        unsigned* __restrict__ smax_key) {
    int ti = blockIdx.y, tj = blockIdx.x;
    if (tj < ti) return;
    __shared__ float Ah[TS][68];
    __shared__ float Bh[TS][68];
    int tid = threadIdx.x;
    int tx = tid & 15, ty = tid >> 4;
    const float* ha = h + (size_t)ti * TS * 128;
    const float* hb = h + (size_t)tj * TS * 128;

    float acc[4][4];
    #pragma unroll
    for (int r = 0; r < 4; ++r)
        #pragma unroll
        for (int c = 0; c < 4; ++c) acc[r][c] = 0.0f;

    for (int half = 0; half < 2; ++half) {
        __syncthreads();
        #pragma unroll
        for (int t = 0; t < 4; ++t) {
            int f = tid + t * 256;
            int row = f >> 4, kk = f & 15;
            *(float4*)&Ah[row][kk * 4] = *(const float4*)(ha + (size_t)row * 128 + half * 64 + kk * 4);
            *(float4*)&Bh[row][kk * 4] = *(const float4*)(hb + (size_t)row * 128 + half * 64 + kk * 4);
        }
        __syncthreads();
        #pragma unroll 2
        for (int k4 = 0; k4 < 16; ++k4) {
            float4 a[4], b[4];
            #pragma unroll
            for (int r = 0; r < 4; ++r) a[r] = *(const float4*)&Ah[ty + 16 * r][k4 * 4];
            #pragma unroll
            for (int c = 0; c < 4; ++c) b[c] = *(const float4*)&Bh[tx + 16 * c][k4 * 4];
            #pragma unroll
            for (int r = 0; r < 4; ++r)
                #pragma unroll
                for (int c = 0; c < 4; ++c) {
                    acc[r][c] = fmaf(a[r].x, b[c].x, acc[r][c]);
                    acc[r][c] = fmaf(a[r].y, b[c].y, acc[r][c]);
                    acc[r][c] = fmaf(a[r].z, b[c].z, acc[r][c]);
                    acc[r][c] = fmaf(a[r].w, b[c].w, acc[r][c]);
                }
        }
    }

    float* sp = S + (size_t)(ti * 64 + tj) * 4096;
    #pragma unroll
    for (int r = 0; r < 4; ++r)
        #pragma unroll
        for (int c = 0; c < 4; ++c)
            sp[(ty + 16 * r) * 64 + tx + 16 * c] = acc[r][c];

    float m = -3.4e38f;
    #pragma unroll
    for (int r = 0; r < 4; ++r)
        #pragma unroll
        for (int c = 0; c < 4; ++c) m = fmaxf(m, acc[r][c]);
    #pragma unroll
    for (int o = 1; o < 64; o <<= 1) m = fmaxf(m, __shfl_xor(m, o, 64));
    __shared__ float wm[4];
    if ((tid & 63) == 0) wm[tid >> 6] = m;
    __syncthreads();
    if (tid == 0)
        atomicMax(smax_key, fkey(fmaxf(fmaxf(wm[0], wm[1]), fmaxf(wm[2], wm[3]))));
}

// Pass 2 (S-store path): read stored S, emit mask bits.
__global__ __launch_bounds__(256, 4) void k_bitemit(const float* __restrict__ S,
                                                    const float* __restrict__ u,
                                                    const unsigned* __restrict__ smax_key,
                                                    unsigned* __restrict__ mb) {
    int ti = blockIdx.y, tj = blockIdx.x;
    if (tj < ti) return;
    int tid = threadIdx.x;
    int tx = tid & 15, ty = tid >> 4;
    float smax = funkey(*smax_key);
    float epmax = 1.0f / (1.0f + expf(-smax));
    __shared__ unsigned lm[TS][2];
    __shared__ unsigned lmT[TS][2];
    if (tid < 128) { lm[tid >> 1][tid & 1] = 0u; lmT[tid >> 1][tid & 1] = 0u; }
    __syncthreads();
    const float* sp = S + (size_t)(ti * 64 + tj) * 4096;
    #pragma unroll
    for (int r = 0; r < 4; ++r) {
        #pragma unroll
        for (int c = 0; c < 4; ++c) {
            int li = ty + 16 * r, lj = tx + 16 * c;
            int gi = ti * TS + li, gj = tj * TS + lj;
            bool bit = false;
            if (gi < gj) {
                float ep = 1.0f / (1.0f + expf(-sp[li * 64 + lj]));
                float P = ep / epmax;
                float Pc = fminf(fmaxf(P, 1e-6f), 1.0f - 1e-6f);
                float uu = u[(size_t)gi * NN + gj];
                float ucv = fminf(fmaxf(uu, 1e-6f), 1.0f - 1e-6f);
                bit = Pc > (1.0f - ucv);
            } else if (gi == gj) {
                bit = true;
            }
            if (bit) {
                atomicOr(&lm[li][lj >> 5], 1u << (lj & 31));
                atomicOr(&lmT[lj][li >> 5], 1u << (li & 31));
            }
        }
    }
    __syncthreads();
    if (tid < 128) {
        int r = tid >> 1, wq = tid & 1;
        unsigned word = lm[r][wq];
        if (ti == tj) word |= lmT[r][wq];
        mb[(size_t)(ti * TS + r) * 128 + tj * 2 + wq] = word;
    } else if (ti != tj) {
        int r = (tid - 128) >> 1, wq = tid & 1;
        mb[(size_t)(tj * TS + r) * 128 + ti * 2 + wq] = lmT[r][wq];
    }
}

// Masked max, D=256, fp16-packed z; fp16-packed partial output (lossless).
template<int RT, int JS>
__global__ __launch_bounds__(256, 8) void k_mmax256h(const unsigned* __restrict__ mb,
                                                     const unsigned* __restrict__ zh,
                                                     unsigned* __restrict__ pmh) {
    constexpr int JPS = NN / JS;   // 512
    constexpr int WPS = JPS / 32;  // 16
    constexpr int RPG = RT / 4;    // 4
    constexpr int NRB = NN / RT;   // 256
    int rowblk = blockIdx.x % NRB, js = blockIdx.x / NRB;
    int i0 = rowblk * RT;

    __shared__ unsigned msk[RT][WPS + 1];
    {
        int t = threadIdx.x;           // RT*WPS == 256
        msk[t / WPS][t % WPS] = mb[(size_t)(i0 + t / WPS) * 128 + js * WPS + t % WPS];
    }
    __syncthreads();

    int d = threadIdx.x & 63;
    int g = threadIdx.x >> 6;
    const uint2* zbase = (const uint2*)zh + (size_t)js * JPS * 64 + d;   // row = 64 uint2

    uint2 acc[RPG];
    #pragma unroll
    for (int r = 0; r < RPG; ++r) acc[r] = make_uint2(0u, 0u);

    #pragma unroll 1
    for (int wq = 0; wq < WPS; ++wq) {
        unsigned m[RPG];
        #pragma unroll
        for (int r = 0; r < RPG; ++r)
            m[r] = (unsigned)__builtin_amdgcn_readfirstlane((int)msk[g * RPG + r][wq]);
        const uint2* zp = zbase + (size_t)(wq * 32) * 64;
        #pragma unroll 2
        for (int j4 = 0; j4 < 32; j4 += 4) {
            uint2 z0 = zp[0 * 64];
            uint2 z1 = zp[1 * 64];
            uint2 z2 = zp[2 * 64];
            uint2 z3 = zp[3 * 64];
            #pragma unroll
            for (int r = 0; r < RPG; ++r) {
                unsigned s0 = bit_sext_s(m[r], j4 + 0);
                unsigned s1 = bit_sext_s(m[r], j4 + 1);
                unsigned s2 = bit_sext_s(m[r], j4 + 2);
                unsigned s3 = bit_sext_s(m[r], j4 + 3);
                pkmax(acc[r].x, s0 & z0.x); pkmax(acc[r].y, s0 & z0.y);
                pkmax(acc[r].x, s1 & z1.x); pkmax(acc[r].y, s1 & z1.y);
                pkmax(acc[r].x, s2 & z2.x); pkmax(acc[r].y, s2 & z2.y);
                pkmax(acc[r].x, s3 & z3.x); pkmax(acc[r].y, s3 & z3.y);
            }
            zp += 4 * 64;
        }
    }

    uint2* po = (uint2*)(pmh + (size_t)js * NN * 128);   // row = 128 u32 = 64 uint2
    #pragma unroll
    for (int r = 0; r < RPG; ++r)
        po[(size_t)(i0 + g * RPG + r) * 64 + d] = acc[r];
}

// Masked max, D=128, fp16-packed z; fp16-packed partial output.
template<int RT, int JS>
__global__ __launch_bounds__(256, 8) void k_mmax128h(const unsigned* __restrict__ mb,
                                                     const unsigned* __restrict__ zh,
                                                     unsigned* __restrict__ pmh) {
    constexpr int JPS = NN / JS;   // 512
    constexpr int WPS = JPS / 32;  // 16
    constexpr int RPG = RT / 4;    // 4
    constexpr int NRB = NN / RT;   // 256
    int rowblk = blockIdx.x % NRB, js = blockIdx.x / NRB;
    int i0 = rowblk * RT;

    __shared__ unsigned msk[RT][WPS + 1];
    {
        int t = threadIdx.x;
        msk[t / WPS][t % WPS] = mb[(size_t)(i0 + t / WPS) * 128 + js * WPS + t % WPS];
    }
    __syncthreads();

    int lane = threadIdx.x & 63;
    int g = threadIdx.x >> 6;
    unsigned jpar = lane >> 5;
    int d2 = lane & 31;                 // uint2 index within row (32 uint2 = 64 u32)
    const uint2* zbase = (const uint2*)zh + (size_t)js * JPS * 32 + d2;

    uint2 acc[RPG];
    #pragma unroll
    for (int r = 0; r < RPG; ++r) acc[r] = make_uint2(0u, 0u);

    #pragma unroll 1
    for (int wq = 0; wq < WPS; ++wq) {
        unsigned m[RPG];
        #pragma unroll
        for (int r = 0; r < RPG; ++r)
            m[r] = (unsigned)__builtin_amdgcn_readfirstlane((int)msk[g * RPG + r][wq]);
        const uint2* zp = zbase + (size_t)(wq * 32) * 32;
        #pragma unroll 2
        for (int j4 = 0; j4 < 32; j4 += 4) {
            uint2 za = zp[(size_t)jpar * 32];
            uint2 zb = zp[(size_t)(2 + jpar) * 32];
            int oa = j4 + (int)jpar, ob = j4 + 2 + (int)jpar;
            #pragma unroll
            for (int r = 0; r < RPG; ++r) {
                unsigned sa = bit_sext_s(m[r], oa);
                unsigned sb = bit_sext_s(m[r], ob);
                pkmax(acc[r].x, sa & za.x); pkmax(acc[r].y, sa & za.y);
                pkmax(acc[r].x, sb & zb.x); pkmax(acc[r].y, sb & zb.y);
            }
            zp += 4 * 32;
        }
    }

    #pragma unroll
    for (int r = 0; r < RPG; ++r) {
        unsigned ox = __shfl_xor(acc[r].x, 32, 64);
        unsigned oy = __shfl_xor(acc[r].y, 32, 64);
        pkmax(acc[r].x, ox);
        pkmax(acc[r].y, oy);
    }
    if (!jpar) {
        uint2* po = (uint2*)(pmh + (size_t)js * NN * 64);   // row = 64 u32 = 32 uint2
        #pragma unroll
        for (int r = 0; r < RPG; ++r)
            po[(size_t)(i0 + g * RPG + r) * 32 + d2] = acc[r];
    }
}

// Final 128->32 GEMM, NS fp16-packed partials, LDS-staged, 4 rows per block.
template<int NS>
__global__ void k_gemm_final(const unsigned* __restrict__ Xh, size_t xstride,
                             const float* __restrict__ W,
                             const float* __restrict__ b1, const float* __restrict__ b2,
                             float* __restrict__ out) {
    __shared__ float xr[4][128];
    int i0 = blockIdx.x * 4;
    for (int t = threadIdx.x; t < 256; t += 128) {
        int r = t >> 6, c = t & 63;
        size_t off = (size_t)(i0 + r) * 64 + c;
        unsigned v = Xh[off];
        #pragma unroll
        for (int s = 1; s < NS; ++s) pkmax(v, Xh[(size_t)s * xstride + off]);
        __half2 h = *(__half2*)&v;
        float2 f = __half22float2(h);
        xr[r][2 * c] = f.x;
        xr[r][2 * c + 1] = f.y;
    }
    __syncthreads();
    int il = threadIdx.x >> 5, j = threadIdx.x & 31;
    float acc = 0.0f;
    #pragma unroll 8
    for (int k = 0; k < 128; ++k) acc = fmaf(xr[il][k], W[k * 32 + j], acc);
    out[(size_t)(i0 + il) * 32 + j] = acc + b1[j] + b2[j];
}

extern "C" void kernel_launch(void* const* d_in, const int* in_sizes, int n_in,
                              void* d_out, int out_size, void* d_ws, size_t ws_size,
                              hipStream_t stream) {
    const float* inputs = (const float*)d_in[1];
    const float* feat   = (const float*)d_in[2];
    const float* u      = (const float*)d_in[3];
    const int*   src    = (const int*)d_in[4];
    const int*   dst    = (const int*)d_in[5];
    const float* gc0W = (const float*)d_in[6],  *gc0b = (const float*)d_in[7];
    const float* gc1W = (const float*)d_in[8],  *gc1b = (const float*)d_in[9];
    const float* p0W  = (const float*)d_in[10], *p0b  = (const float*)d_in[11];
    const float* l0W  = (const float*)d_in[12], *l0b  = (const float*)d_in[13];
    const float* b0   = (const float*)d_in[14];
    const float* p1W  = (const float*)d_in[15], *p1b  = (const float*)d_in[16];
    const float* l1W  = (const float*)d_in[17], *l1b  = (const float*)d_in[18];
    const float* b1   = (const float*)d_in[19];
    const float* p2W  = (const float*)d_in[20], *p2b  = (const float*)d_in[21];
    const float* l2W  = (const float*)d_in[22], *l2b  = (const float*)d_in[23];
    const float* b2   = (const float*)d_in[24];
    float* out = (float*)d_out;

    const size_t MB = 1048576;
    char* w = (char*)d_ws;
    int*      cnt_src  = (int*)(w + 0);            // 16 KB
    int*      cnt_dst  = (int*)(w + 16384);        // 16 KB
    float*    on       = (float*)(w + 32768);      // 16 KB
    float*    inn      = (float*)(w + 49152);      // 16 KB
    unsigned* smax_key = (unsigned*)(w + 65536);   // pad to 128 KB
    char*     big      = w + 131072;
    float*    tmp      = (float*)(big);            // 2 MB
    float*    agg      = (float*)(big + 2 * MB);   // 2 MB
    float*    hbuf     = (float*)(big + 4 * MB);   // 2 MB
    unsigned* mb       = (unsigned*)(big + 6 * MB);// 2 MB
    unsigned* zh       = (unsigned*)(big + 8 * MB);// 2 MB (fp16-packed z)
    unsigned* pmh      = (unsigned*)(big + 12 * MB);// 16 MB (8 fp16 split partials)
    float*    hs       = (float*)(big + 44 * MB);  // 2 MB
    float*    Sbuf     = (float*)(big + 46 * MB);  // 64 MB
    bool use_sstore = ws_size >= 131072 + 110 * MB;

    hipMemsetAsync(w, 0, 131072, stream);
    k_count<<<EE / 256, 256, 0, stream>>>(src, dst, cnt_src, cnt_dst);
    k_norm<<<NN / 256, 256, 0, stream>>>(cnt_src, cnt_dst, on, inn);

    // --- GCN layer 0 ---
    k_gemm_scale<256, 128, 4><<<NN / 4, 128, 0, stream>>>(inputs, gc0W, on, tmp);
    hipMemsetAsync(agg, 0, (size_t)NN * 128 * 4, stream);
    k_scatter<<<EE, 128, 0, stream>>>(tmp, src, dst, agg);
    k_gcn_out<<<NN * 128 / 256, 256, 0, stream>>>(agg, inn, gc0b, hbuf, 1);

    // --- GCN layer 1 ---
    k_gemm_scale<128, 128, 4><<<NN / 4, 128, 0, stream>>>(hbuf, gc1W, on, tmp);
    hipMemsetAsync(agg, 0, (size_t)NN * 128 * 4, stream);
    k_scatter<<<EE, 128, 0, stream>>>(tmp, src, dst, agg);
    k_gcn_out<<<NN * 128 / 256, 256, 0, stream>>>(agg, inn, gc1b, hbuf, 0);

    // --- decode: S max + mask bits ---
    dim3 tg(64, 64);
    if (use_sstore) {
        k_stile_store<<<tg, 256, 0, stream>>>(hbuf, Sbuf, smax_key);
        k_bitemit<<<tg, 256, 0, stream>>>(Sbuf, u, smax_key, mb);
    } else {
        k_stile<0><<<tg, 256, 0, stream>>>(hbuf, nullptr, smax_key, nullptr);
        k_stile<1><<<tg, 256, 0, stream>>>(hbuf, u, smax_key, mb);
    }

    // --- GraphSAGE layer 0 (256 -> 128), fp16 masked max + fp16 partials ---
    k_gemm_ab<256, 256, 4, 1><<<NN / 4, 256, 0, stream>>>(feat, p0W, p0b, (float*)zh);
    k_mmax256h<16, 8><<<(NN / 16) * 8, 256, 0, stream>>>(mb, zh, pmh);
    k_gemm_mrgh<256, 128, 8, 4, 1><<<NN / 4, 128, 0, stream>>>(pmh, (size_t)NN * 128, l0W, l0b, b0, hs);

    // --- GraphSAGE layer 1 (128 -> 128) ---
    k_gemm_ab<128, 128, 4, 1><<<NN / 4, 128, 0, stream>>>(hs, p1W, p1b, (float*)zh);
    k_mmax128h<16, 8><<<(NN / 16) * 8, 256, 0, stream>>>(mb, zh, pmh);
    k_gemm_mrgh<128, 128, 8, 4, 1><<<NN / 4, 128, 0, stream>>>(pmh, (size_t)NN * 64, l1W, l1b, b1, tmp);

    // --- GraphSAGE layer 2 (128 -> 32) ---
    k_gemm_ab<128, 128, 4, 1><<<NN / 4, 128, 0, stream>>>(tmp, p2W, p2b, (float*)zh);
    k_mmax128h<16, 8><<<(NN / 16) * 8, 256, 0, stream>>>(mb, zh, pmh);
    k_gemm_final<8><<<NN / 4, 128, 0, stream>>>(pmh, (size_t)NN * 64, l2W, l2b, b2, out);
}

// Round 19
// 576.814 us; speedup vs baseline: 1.3485x; 1.1620x over previous
//
#include <hip/hip_runtime.h>
#include <hip/hip_fp16.h>
#include <cstdint>
#include <cstddef>

#define NN 4096
#define EE 131072
#define TS 64

__device__ __forceinline__ unsigned fkey(float f) {
    unsigned u = __float_as_uint(f);
    return (u & 0x80000000u) ? ~u : (u | 0x80000000u);
}
__device__ __forceinline__ float funkey(unsigned k) {
    unsigned u = (k & 0x80000000u) ? (k & 0x7fffffffu) : ~k;
    return __uint_as_float(u);
}

// ---- VALU-only asm pins (no SALU/SCC writes; proven safe rounds 14-18) ----
__device__ __forceinline__ void pkmax(unsigned& a, unsigned x) {
    asm("v_pk_max_f16 %0, %0, %1" : "+v"(a) : "v"(x));
}
__device__ __forceinline__ unsigned bit_sext_s(unsigned w, int off) {
    return (unsigned)(((int)(w << (31 - off))) >> 31);
}

__global__ void k_count(const int* __restrict__ src, const int* __restrict__ dst,
                        int* __restrict__ cs, int* __restrict__ cd) {
    int e = blockIdx.x * 256 + threadIdx.x;
    if (e < EE) {
        atomicAdd(&cs[src[e]], 1);
        atomicAdd(&cd[dst[e]], 1);
    }
}

__global__ void k_norm(const int* __restrict__ cs, const int* __restrict__ cd,
                       float* __restrict__ on, float* __restrict__ inn) {
    int i = blockIdx.x * 256 + threadIdx.x;
    if (i < NN) {
        int a = cs[i] > 1 ? cs[i] : 1;
        int b = cd[i] > 1 ? cd[i] : 1;
        on[i]  = 1.0f / sqrtf((float)a);
        inn[i] = 1.0f / sqrtf((float)b);
    }
}

// Exclusive prefix sum of cnt_dst (4096) -> off[0..4096]. One block, 1024 thr.
__global__ void k_prefix(const int* __restrict__ cnt, int* __restrict__ off) {
    __shared__ int ls[1024];
    int t = threadIdx.x;
    int base[4];
    int s = 0;
    #pragma unroll
    for (int k = 0; k < 4; ++k) { base[k] = s; s += cnt[t * 4 + k]; }
    ls[t] = s;
    __syncthreads();
    for (int o = 1; o < 1024; o <<= 1) {
        int v = (t >= o) ? ls[t - o] : 0;
        __syncthreads();
        ls[t] += v;
        __syncthreads();
    }
    int excl = (t == 0) ? 0 : ls[t - 1];
    #pragma unroll
    for (int k = 0; k < 4; ++k) off[t * 4 + k] = excl + base[k];
    if (t == 1023) off[4096] = ls[1023];
}

// Bucket edges by dst: elist[off[d] + cursor[d]++] = src.
__global__ void k_bucket(const int* __restrict__ src, const int* __restrict__ dst,
                         const int* __restrict__ off, int* __restrict__ cursor,
                         int* __restrict__ elist) {
    int e = blockIdx.x * 256 + threadIdx.x;
    if (e < EE) {
        int d = dst[e];
        int pos = atomicAdd(&cursor[d], 1);
        elist[off[d] + pos] = src[e];
    }
}

// CSR gather segment-sum + GCN epilogue: out[d][j] = (sum_{s in N(d)} t[s][j])
// * inn[d] + b[j], optional relu. Block per dst row, 128 threads, 4 acc chains.
__global__ void k_gather(const float* __restrict__ t, const int* __restrict__ elist,
                         const int* __restrict__ off, const float* __restrict__ inn,
                         const float* __restrict__ b, float* __restrict__ outp,
                         int do_relu) {
    int d = blockIdx.x;
    int j = threadIdx.x;
    int s0 = off[d], s1 = off[d + 1];
    float a0 = 0.f, a1 = 0.f, a2 = 0.f, a3 = 0.f;
    int e = s0;
    for (; e + 4 <= s1; e += 4) {
        a0 += t[(size_t)elist[e + 0] * 128 + j];
        a1 += t[(size_t)elist[e + 1] * 128 + j];
        a2 += t[(size_t)elist[e + 2] * 128 + j];
        a3 += t[(size_t)elist[e + 3] * 128 + j];
    }
    for (; e < s1; ++e) a0 += t[(size_t)elist[e] * 128 + j];
    float v = ((a0 + a1) + (a2 + a3)) * inn[d] + b[j];
    if (do_relu) v = fmaxf(v, 0.0f);
    outp[(size_t)d * 128 + j] = v;
}

// RB rows per block: W[k][j] read once per block for RB rows.
template<int K, int ND, int RB>
__global__ void k_gemm_scale(const float* __restrict__ X, const float* __restrict__ W,
                             const float* __restrict__ scale, float* __restrict__ out) {
    __shared__ float xr[RB][K];
    int i0 = blockIdx.x * RB;
    for (int t = threadIdx.x; t < RB * K; t += ND)
        xr[t / K][t % K] = X[(size_t)(i0 + t / K) * K + t % K];
    __syncthreads();
    int j = threadIdx.x;
    float acc[RB];
    #pragma unroll
    for (int r = 0; r < RB; ++r) acc[r] = 0.0f;
    #pragma unroll 4
    for (int k = 0; k < K; ++k) {
        float w = W[k * ND + j];
        #pragma unroll
        for (int r = 0; r < RB; ++r) acc[r] = fmaf(xr[r][k], w, acc[r]);
    }
    #pragma unroll
    for (int r = 0; r < RB; ++r)
        out[(size_t)(i0 + r) * ND + j] = acc[r] * scale[i0 + r];
}

// f32-input GEMM, RB rows/block. H16=1: relu + packed-half2 output.
template<int K, int ND, int RB, int H16>
__global__ void k_gemm_ab(const float* __restrict__ X, const float* __restrict__ W,
                          const float* __restrict__ b1, float* __restrict__ out) {
    __shared__ float xr[RB][K];
    int i0 = blockIdx.x * RB;
    for (int t = threadIdx.x; t < RB * K; t += ND)
        xr[t / K][t % K] = X[(size_t)(i0 + t / K) * K + t % K];
    __syncthreads();
    int j = threadIdx.x;
    float acc[RB];
    #pragma unroll
    for (int r = 0; r < RB; ++r) acc[r] = 0.0f;
    #pragma unroll 4
    for (int k = 0; k < K; ++k) {
        float w = W[k * ND + j];
        #pragma unroll
        for (int r = 0; r < RB; ++r) acc[r] = fmaf(xr[r][k], w, acc[r]);
    }
    if constexpr (H16) {
        unsigned* oh = (unsigned*)out;
        #pragma unroll
        for (int r = 0; r < RB; ++r) {
            float v = fmaxf(acc[r] + b1[j], 0.0f);
            float o2 = __shfl_xor(v, 1, 64);
            if ((j & 1) == 0) {
                __half2 h = __floats2half2_rn(v, o2);
                oh[(size_t)(i0 + r) * (ND / 2) + (j >> 1)] = *(unsigned*)&h;
            }
        }
    } else {
        #pragma unroll
        for (int r = 0; r < RB; ++r)
            out[(size_t)(i0 + r) * ND + j] = acc[r] + b1[j];
    }
}

// Merge GEMM from NS fp16-packed partials (packed pkmax merge, lossless),
// then f32 GEMM. L2N=1: fused relu + l2-normalize epilogue.
template<int K, int ND, int NS, int RB, int L2N>
__global__ void k_gemm_mrgh(const unsigned* __restrict__ Xh, size_t xstride,
                            const float* __restrict__ W,
                            const float* __restrict__ b1, const float* __restrict__ b2,
                            float* __restrict__ out) {
    __shared__ float xr[RB][K];
    int i0 = blockIdx.x * RB;
    for (int t = threadIdx.x; t < RB * (K / 2); t += ND) {
        int r = t / (K / 2), c = t % (K / 2);
        size_t off = (size_t)(i0 + r) * (K / 2) + c;
        unsigned v = Xh[off];
        #pragma unroll
        for (int s = 1; s < NS; ++s) pkmax(v, Xh[(size_t)s * xstride + off]);
        __half2 h = *(__half2*)&v;
        float2 f = __half22float2(h);
        xr[r][2 * c] = f.x;
        xr[r][2 * c + 1] = f.y;
    }
    __syncthreads();
    int j = threadIdx.x;
    float acc[RB];
    #pragma unroll
    for (int r = 0; r < RB; ++r) acc[r] = 0.0f;
    #pragma unroll 4
    for (int k = 0; k < K; ++k) {
        float w = W[k * ND + j];
        #pragma unroll
        for (int r = 0; r < RB; ++r) acc[r] = fmaf(xr[r][k], w, acc[r]);
    }
    if constexpr (L2N) {
        float v[RB], ss[RB];
        #pragma unroll
        for (int r = 0; r < RB; ++r) {
            float t = acc[r] + b1[j];
            if (b2) t += b2[j];
            v[r] = fmaxf(t, 0.0f);
            ss[r] = v[r] * v[r];
        }
        #pragma unroll
        for (int o = 1; o < 64; o <<= 1)
            #pragma unroll
            for (int r = 0; r < RB; ++r) ss[r] += __shfl_xor(ss[r], o, 64);
        __shared__ float sred[RB][2];
        if ((threadIdx.x & 63) == 0)
            #pragma unroll
            for (int r = 0; r < RB; ++r) sred[r][threadIdx.x >> 6] = ss[r];
        __syncthreads();
        #pragma unroll
        for (int r = 0; r < RB; ++r) {
            float tot = sred[r][0] + sred[r][1];
            out[(size_t)(i0 + r) * ND + j] = v[r] / fmaxf(sqrtf(tot), 1e-12f);
        }
    } else {
        #pragma unroll
        for (int r = 0; r < RB; ++r) {
            float v = acc[r] + b1[j];
            if (b2) v += b2[j];
            out[(size_t)(i0 + r) * ND + j] = v;
        }
    }
}

// ---- S = h h^T 64x64 tile; MODE 0: max-only; MODE 1: recompute + bit-emit ----
template<int MODE>
__global__ __launch_bounds__(256, 4) void k_stile(const float* __restrict__ h,
                                                  const float* __restrict__ u,
                                                  unsigned* __restrict__ smax_key,
                                                  unsigned* __restrict__ mb) {
    int ti = blockIdx.y, tj = blockIdx.x;
    if (tj < ti) return;
    __shared__ float Ah[TS][68];
    __shared__ float Bh[TS][68];
    int tid = threadIdx.x;
    int tx = tid & 15, ty = tid >> 4;
    const float* ha = h + (size_t)ti * TS * 128;
    const float* hb = h + (size_t)tj * TS * 128;

    float acc[4][4];
    #pragma unroll
    for (int r = 0; r < 4; ++r)
        #pragma unroll
        for (int c = 0; c < 4; ++c) acc[r][c] = 0.0f;

    for (int half = 0; half < 2; ++half) {
        __syncthreads();
        #pragma unroll
        for (int t = 0; t < 4; ++t) {
            int f = tid + t * 256;
            int row = f >> 4, kk = f & 15;
            *(float4*)&Ah[row][kk * 4] = *(const float4*)(ha + (size_t)row * 128 + half * 64 + kk * 4);
            *(float4*)&Bh[row][kk * 4] = *(const float4*)(hb + (size_t)row * 128 + half * 64 + kk * 4);
        }
        __syncthreads();
        #pragma unroll 2
        for (int k4 = 0; k4 < 16; ++k4) {
            float4 a[4], b[4];
            #pragma unroll
            for (int r = 0; r < 4; ++r) a[r] = *(const float4*)&Ah[ty + 16 * r][k4 * 4];
            #pragma unroll
            for (int c = 0; c < 4; ++c) b[c] = *(const float4*)&Bh[tx + 16 * c][k4 * 4];
            #pragma unroll
            for (int r = 0; r < 4; ++r)
                #pragma unroll
                for (int c = 0; c < 4; ++c) {
                    acc[r][c] = fmaf(a[r].x, b[c].x, acc[r][c]);
                    acc[r][c] = fmaf(a[r].y, b[c].y, acc[r][c]);
                    acc[r][c] = fmaf(a[r].z, b[c].z, acc[r][c]);
                    acc[r][c] = fmaf(a[r].w, b[c].w, acc[r][c]);
                }
        }
    }

    if constexpr (MODE == 0) {
        float m = -3.4e38f;
        #pragma unroll
        for (int r = 0; r < 4; ++r)
            #pragma unroll
            for (int c = 0; c < 4; ++c) m = fmaxf(m, acc[r][c]);
        #pragma unroll
        for (int o = 1; o < 64; o <<= 1) m = fmaxf(m, __shfl_xor(m, o, 64));
        __shared__ float wm[4];
        if ((tid & 63) == 0) wm[tid >> 6] = m;
        __syncthreads();
        if (tid == 0) {
            float mm = fmaxf(fmaxf(wm[0], wm[1]), fmaxf(wm[2], wm[3]));
            atomicMax(smax_key, fkey(mm));
        }
    } else {
        float smax = funkey(*smax_key);
        float epmax = 1.0f / (1.0f + expf(-smax));
        __shared__ unsigned lm[TS][2];
        __shared__ unsigned lmT[TS][2];
        if (tid < 128) { lm[tid >> 1][tid & 1] = 0u; lmT[tid >> 1][tid & 1] = 0u; }
        __syncthreads();
        #pragma unroll
        for (int r = 0; r < 4; ++r) {
            #pragma unroll
            for (int c = 0; c < 4; ++c) {
                int li = ty + 16 * r, lj = tx + 16 * c;
                int gi = ti * TS + li, gj = tj * TS + lj;
                bool bit = false;
                if (gi < gj) {
                    float ep = 1.0f / (1.0f + expf(-acc[r][c]));
                    float P = ep / epmax;
                    float Pc = fminf(fmaxf(P, 1e-6f), 1.0f - 1e-6f);
                    float uu = u[(size_t)gi * NN + gj];
                    float ucv = fminf(fmaxf(uu, 1e-6f), 1.0f - 1e-6f);
                    bit = Pc > (1.0f - ucv);
                } else if (gi == gj) {
                    bit = true;
                }
                if (bit) {
                    atomicOr(&lm[li][lj >> 5], 1u << (lj & 31));
                    atomicOr(&lmT[lj][li >> 5], 1u << (li & 31));
                }
            }
        }
        __syncthreads();
        if (tid < 128) {
            int r = tid >> 1, wq = tid & 1;
            unsigned word = lm[r][wq];
            if (ti == tj) word |= lmT[r][wq];
            mb[(size_t)(ti * TS + r) * 128 + tj * 2 + wq] = word;
        } else if (ti != tj) {
            int r = (tid - 128) >> 1, wq = tid & 1;
            mb[(size_t)(tj * TS + r) * 128 + ti * 2 + wq] = lmT[r][wq];
        }
    }
}

// Pass 1 (S-store path): compute tile, store S to ws, fold into global max.
__global__ __launch_bounds__(256, 4) void k_stile_store(const float* __restrict__ h,
                                                        float* __restrict__ S,
                                                        unsigned* __restrict__ smax_key) {
    int ti = blockIdx.y, tj = blockIdx.x;
    if (tj < ti) return;
    __shared__ float Ah[TS][68];
    __shared__ float Bh[TS][68];
    int tid = threadIdx.x;
    int tx = tid & 15, ty = tid >> 4;
    const float* ha = h + (size_t)ti * TS * 128;
    const float* hb = h + (size_t)tj * TS * 128;

    float acc[4][4];
    #pragma unroll
    for (int r = 0; r < 4; ++r)
        #pragma unroll
        for (int c = 0; c < 4; ++c) acc[r][c] = 0.0f;

    for (int half = 0; half < 2; ++half) {
        __syncthreads();
        #pragma unroll
        for (int t = 0; t < 4; ++t) {
            int f = tid + t * 256;
            int row = f >> 4, kk = f & 15;
            *(float4*)&Ah[row][kk * 4] = *(const float4*)(ha + (size_t)row * 128 + half * 64 + kk * 4);
            *(float4*)&Bh[row][kk * 4] = *(const float4*)(hb + (size_t)row * 128 + half * 64 + kk * 4);
        }
        __syncthreads();
        #pragma unroll 2
        for (int k4 = 0; k4 < 16; ++k4) {
            float4 a[4], b[4];
            #pragma unroll
            for (int r = 0; r < 4; ++r) a[r] = *(const float4*)&Ah[ty + 16 * r][k4 * 4];
            #pragma unroll
            for (int c = 0; c < 4; ++c) b[c] = *(const float4*)&Bh[tx + 16 * c][k4 * 4];
            #pragma unroll
            for (int r = 0; r < 4; ++r)
                #pragma unroll
                for (int c = 0; c < 4; ++c) {
                    acc[r][c] = fmaf(a[r].x, b[c].x, acc[r][c]);
                    acc[r][c] = fmaf(a[r].y, b[c].y, acc[r][c]);
                    acc[r][c] = fmaf(a[r].z, b[c].z, acc[r][c]);
                    acc[r][c] = fmaf(a[r].w, b[c].w, acc[r][c]);
                }
        }
    }

    float* sp = S + (size_t)(ti * 64 + tj) * 4096;
    #pragma unroll
    for (int r = 0; r < 4; ++r)
        #pragma unroll
        for (int c = 0; c < 4; ++c)
            sp[(ty + 16 * r) * 64 + tx + 16 * c] = acc[r][c];

    float m = -3.4e38f;
    #pragma unroll
    for (int r = 0; r < 4; ++r)
        #pragma unroll
        for (int c = 0; c < 4; ++c) m = fmaxf(m, acc[r][c]);
    #pragma unroll
    for (int o = 1; o < 64; o <<= 1) m = fmaxf(m, __shfl_xor(m, o, 64));
    __shared__ float wm[4];
    if ((tid & 63) == 0) wm[tid >> 6] = m;
    __syncthreads();
    if (tid == 0)
        atomicMax(smax_key, fkey(fmaxf(fmaxf(wm[0], wm[1]), fmaxf(wm[2], wm[3]))));
}

// Pass 2 (S-store path): read stored S, emit mask bits.
__global__ __launch_bounds__(256, 4) void k_bitemit(const float* __restrict__ S,
                                                    const float* __restrict__ u,
                                                    const unsigned* __restrict__ smax_key,
                                                    unsigned* __restrict__ mb) {
    int ti = blockIdx.y, tj = blockIdx.x;
    if (tj < ti) return;
    int tid = threadIdx.x;
    int tx = tid & 15, ty = tid >> 4;
    float smax = funkey(*smax_key);
    float epmax = 1.0f / (1.0f + expf(-smax));
    __shared__ unsigned lm[TS][2];
    __shared__ unsigned lmT[TS][2];
    if (tid < 128) { lm[tid >> 1][tid & 1] = 0u; lmT[tid >> 1][tid & 1] = 0u; }
    __syncthreads();
    const float* sp = S + (size_t)(ti * 64 + tj) * 4096;
    #pragma unroll
    for (int r = 0; r < 4; ++r) {
        #pragma unroll
        for (int c = 0; c < 4; ++c) {
            int li = ty + 16 * r, lj = tx + 16 * c;
            int gi = ti * TS + li, gj = tj * TS + lj;
            bool bit = false;
            if (gi < gj) {
                float ep = 1.0f / (1.0f + expf(-sp[li * 64 + lj]));
                float P = ep / epmax;
                float Pc = fminf(fmaxf(P, 1e-6f), 1.0f - 1e-6f);
                float uu = u[(size_t)gi * NN + gj];
                float ucv = fminf(fmaxf(uu, 1e-6f), 1.0f - 1e-6f);
                bit = Pc > (1.0f - ucv);
            } else if (gi == gj) {
                bit = true;
            }
            if (bit) {
                atomicOr(&lm[li][lj >> 5], 1u << (lj & 31));
                atomicOr(&lmT[lj][li >> 5], 1u << (li & 31));
            }
        }
    }
    __syncthreads();
    if (tid < 128) {
        int r = tid >> 1, wq = tid & 1;
        unsigned word = lm[r][wq];
        if (ti == tj) word |= lmT[r][wq];
        mb[(size_t)(ti * TS + r) * 128 + tj * 2 + wq] = word;
    } else if (ti != tj) {
        int r = (tid - 128) >> 1, wq = tid & 1;
        mb[(size_t)(tj * TS + r) * 128 + ti * 2 + wq] = lmT[r][wq];
    }
}

// Masked max, D=256, fp16-packed z; fp16-packed partial output (lossless).
template<int RT, int JS>
__global__ __launch_bounds__(256, 8) void k_mmax256h(const unsigned* __restrict__ mb,
                                                     const unsigned* __restrict__ zh,
                                                     unsigned* __restrict__ pmh) {
    constexpr int JPS = NN / JS;   // 512
    constexpr int WPS = JPS / 32;  // 16
    constexpr int RPG = RT / 4;    // 4
    constexpr int NRB = NN / RT;   // 256
    int rowblk = blockIdx.x % NRB, js = blockIdx.x / NRB;
    int i0 = rowblk * RT;

    __shared__ unsigned msk[RT][WPS + 1];
    {
        int t = threadIdx.x;           // RT*WPS == 256
        msk[t / WPS][t % WPS] = mb[(size_t)(i0 + t / WPS) * 128 + js * WPS + t % WPS];
    }
    __syncthreads();

    int d = threadIdx.x & 63;
    int g = threadIdx.x >> 6;
    const uint2* zbase = (const uint2*)zh + (size_t)js * JPS * 64 + d;   // row = 64 uint2

    uint2 acc[RPG];
    #pragma unroll
    for (int r = 0; r < RPG; ++r) acc[r] = make_uint2(0u, 0u);

    #pragma unroll 1
    for (int wq = 0; wq < WPS; ++wq) {
        unsigned m[RPG];
        #pragma unroll
        for (int r = 0; r < RPG; ++r)
            m[r] = (unsigned)__builtin_amdgcn_readfirstlane((int)msk[g * RPG + r][wq]);
        const uint2* zp = zbase + (size_t)(wq * 32) * 64;
        #pragma unroll 2
        for (int j4 = 0; j4 < 32; j4 += 4) {
            uint2 z0 = zp[0 * 64];
            uint2 z1 = zp[1 * 64];
            uint2 z2 = zp[2 * 64];
            uint2 z3 = zp[3 * 64];
            #pragma unroll
            for (int r = 0; r < RPG; ++r) {
                unsigned s0 = bit_sext_s(m[r], j4 + 0);
                unsigned s1 = bit_sext_s(m[r], j4 + 1);
                unsigned s2 = bit_sext_s(m[r], j4 + 2);
                unsigned s3 = bit_sext_s(m[r], j4 + 3);
                pkmax(acc[r].x, s0 & z0.x); pkmax(acc[r].y, s0 & z0.y);
                pkmax(acc[r].x, s1 & z1.x); pkmax(acc[r].y, s1 & z1.y);
                pkmax(acc[r].x, s2 & z2.x); pkmax(acc[r].y, s2 & z2.y);
                pkmax(acc[r].x, s3 & z3.x); pkmax(acc[r].y, s3 & z3.y);
            }
            zp += 4 * 64;
        }
    }

    uint2* po = (uint2*)(pmh + (size_t)js * NN * 128);   // row = 128 u32 = 64 uint2
    #pragma unroll
    for (int r = 0; r < RPG; ++r)
        po[(size_t)(i0 + g * RPG + r) * 64 + d] = acc[r];
}

// Masked max, D=128, fp16-packed z; fp16-packed partial output.
template<int RT, int JS>
__global__ __launch_bounds__(256, 8) void k_mmax128h(const unsigned* __restrict__ mb,
                                                     const unsigned* __restrict__ zh,
                                                     unsigned* __restrict__ pmh) {
    constexpr int JPS = NN / JS;   // 512
    constexpr int WPS = JPS / 32;  // 16
    constexpr int RPG = RT / 4;    // 4
    constexpr int NRB = NN / RT;   // 256
    int rowblk = blockIdx.x % NRB, js = blockIdx.x / NRB;
    int i0 = rowblk * RT;

    __shared__ unsigned msk[RT][WPS + 1];
    {
        int t = threadIdx.x;
        msk[t / WPS][t % WPS] = mb[(size_t)(i0 + t / WPS) * 128 + js * WPS + t % WPS];
    }
    __syncthreads();

    int lane = threadIdx.x & 63;
    int g = threadIdx.x >> 6;
    unsigned jpar = lane >> 5;
    int d2 = lane & 31;                 // uint2 index within row (32 uint2 = 64 u32)
    const uint2* zbase = (const uint2*)zh + (size_t)js * JPS * 32 + d2;

    uint2 acc[RPG];
    #pragma unroll
    for (int r = 0; r < RPG; ++r) acc[r] = make_uint2(0u, 0u);

    #pragma unroll 1
    for (int wq = 0; wq < WPS; ++wq) {
        unsigned m[RPG];
        #pragma unroll
        for (int r = 0; r < RPG; ++r)
            m[r] = (unsigned)__builtin_amdgcn_readfirstlane((int)msk[g * RPG + r][wq]);
        const uint2* zp = zbase + (size_t)(wq * 32) * 32;
        #pragma unroll 2
        for (int j4 = 0; j4 < 32; j4 += 4) {
            uint2 za = zp[(size_t)jpar * 32];
            uint2 zb = zp[(size_t)(2 + jpar) * 32];
            int oa = j4 + (int)jpar, ob = j4 + 2 + (int)jpar;
            #pragma unroll
            for (int r = 0; r < RPG; ++r) {
                unsigned sa = bit_sext_s(m[r], oa);
                unsigned sb = bit_sext_s(m[r], ob);
                pkmax(acc[r].x, sa & za.x); pkmax(acc[r].y, sa & za.y);
                pkmax(acc[r].x, sb & zb.x); pkmax(acc[r].y, sb & zb.y);
            }
            zp += 4 * 32;
        }
    }

    #pragma unroll
    for (int r = 0; r < RPG; ++r) {
        unsigned ox = __shfl_xor(acc[r].x, 32, 64);
        unsigned oy = __shfl_xor(acc[r].y, 32, 64);
        pkmax(acc[r].x, ox);
        pkmax(acc[r].y, oy);
    }
    if (!jpar) {
        uint2* po = (uint2*)(pmh + (size_t)js * NN * 64);   // row = 64 u32 = 32 uint2
        #pragma unroll
        for (int r = 0; r < RPG; ++r)
            po[(size_t)(i0 + g * RPG + r) * 32 + d2] = acc[r];
    }
}

// Final 128->32 GEMM, NS fp16-packed partials, LDS-staged, 4 rows per block.
template<int NS>
__global__ void k_gemm_final(const unsigned* __restrict__ Xh, size_t xstride,
                             const float* __restrict__ W,
                             const float* __restrict__ b1, const float* __restrict__ b2,
                             float* __restrict__ out) {
    __shared__ float xr[4][128];
    int i0 = blockIdx.x * 4;
    for (int t = threadIdx.x; t < 256; t += 128) {
        int r = t >> 6, c = t & 63;
        size_t off = (size_t)(i0 + r) * 64 + c;
        unsigned v = Xh[off];
        #pragma unroll
        for (int s = 1; s < NS; ++s) pkmax(v, Xh[(size_t)s * xstride + off]);
        __half2 h = *(__half2*)&v;
        float2 f = __half22float2(h);
        xr[r][2 * c] = f.x;
        xr[r][2 * c + 1] = f.y;
    }
    __syncthreads();
    int il = threadIdx.x >> 5, j = threadIdx.x & 31;
    float acc = 0.0f;
    #pragma unroll 8
    for (int k = 0; k < 128; ++k) acc = fmaf(xr[il][k], W[k * 32 + j], acc);
    out[(size_t)(i0 + il) * 32 + j] = acc + b1[j] + b2[j];
}

extern "C" void kernel_launch(void* const* d_in, const int* in_sizes, int n_in,
                              void* d_out, int out_size, void* d_ws, size_t ws_size,
                              hipStream_t stream) {
    const float* inputs = (const float*)d_in[1];
    const float* feat   = (const float*)d_in[2];
    const float* u      = (const float*)d_in[3];
    const int*   src    = (const int*)d_in[4];
    const int*   dst    = (const int*)d_in[5];
    const float* gc0W = (const float*)d_in[6],  *gc0b = (const float*)d_in[7];
    const float* gc1W = (const float*)d_in[8],  *gc1b = (const float*)d_in[9];
    const float* p0W  = (const float*)d_in[10], *p0b  = (const float*)d_in[11];
    const float* l0W  = (const float*)d_in[12], *l0b  = (const float*)d_in[13];
    const float* b0   = (const float*)d_in[14];
    const float* p1W  = (const float*)d_in[15], *p1b  = (const float*)d_in[16];
    const float* l1W  = (const float*)d_in[17], *l1b  = (const float*)d_in[18];
    const float* b1   = (const float*)d_in[19];
    const float* p2W  = (const float*)d_in[20], *p2b  = (const float*)d_in[21];
    const float* l2W  = (const float*)d_in[22], *l2b  = (const float*)d_in[23];
    const float* b2   = (const float*)d_in[24];
    float* out = (float*)d_out;

    const size_t MB = 1048576;
    char* w = (char*)d_ws;
    int*      cnt_src  = (int*)(w + 0);            // 16 KB
    int*      cnt_dst  = (int*)(w + 16384);        // 16 KB
    float*    on       = (float*)(w + 32768);      // 16 KB
    float*    inn      = (float*)(w + 49152);      // 16 KB
    unsigned* smax_key = (unsigned*)(w + 65536);   // 4 B (padded)
    int*      cursor   = (int*)(w + 81920);        // 16 KB
    int*      eoff     = (int*)(w + 98304);        // 16.4 KB (4097 ints)
    char*     big      = w + 131072;
    float*    tmp      = (float*)(big);            // 2 MB
    int*      elist    = (int*)(big + 2 * MB);     // 512 KB (in old agg slot)
    float*    hbuf     = (float*)(big + 4 * MB);   // 2 MB
    unsigned* mb       = (unsigned*)(big + 6 * MB);// 2 MB
    unsigned* zh       = (unsigned*)(big + 8 * MB);// 2 MB (fp16-packed z)
    unsigned* pmh      = (unsigned*)(big + 12 * MB);// 16 MB (8 fp16 split partials)
    float*    hs       = (float*)(big + 44 * MB);  // 2 MB
    float*    Sbuf     = (float*)(big + 46 * MB);  // 64 MB
    bool use_sstore = ws_size >= 131072 + 110 * MB;

    // zero counts + cursor + smax key
    hipMemsetAsync(w, 0, 131072, stream);
    k_count<<<EE / 256, 256, 0, stream>>>(src, dst, cnt_src, cnt_dst);
    k_norm<<<NN / 256, 256, 0, stream>>>(cnt_src, cnt_dst, on, inn);
    k_prefix<<<1, 1024, 0, stream>>>(cnt_dst, eoff);
    k_bucket<<<EE / 256, 256, 0, stream>>>(src, dst, eoff, cursor, elist);

    // --- GCN layer 0 ---
    k_gemm_scale<256, 128, 4><<<NN / 4, 128, 0, stream>>>(inputs, gc0W, on, tmp);
    k_gather<<<NN, 128, 0, stream>>>(tmp, elist, eoff, inn, gc0b, hbuf, 1);

    // --- GCN layer 1 ---
    k_gemm_scale<128, 128, 4><<<NN / 4, 128, 0, stream>>>(hbuf, gc1W, on, tmp);
    k_gather<<<NN, 128, 0, stream>>>(tmp, elist, eoff, inn, gc1b, hbuf, 0);

    // --- decode: S max + mask bits ---
    dim3 tg(64, 64);
    if (use_sstore) {
        k_stile_store<<<tg, 256, 0, stream>>>(hbuf, Sbuf, smax_key);
        k_bitemit<<<tg, 256, 0, stream>>>(Sbuf, u, smax_key, mb);
    } else {
        k_stile<0><<<tg, 256, 0, stream>>>(hbuf, nullptr, smax_key, nullptr);
        k_stile<1><<<tg, 256, 0, stream>>>(hbuf, u, smax_key, mb);
    }

    // --- GraphSAGE layer 0 (256 -> 128), fp16 masked max + fp16 partials ---
    k_gemm_ab<256, 256, 4, 1><<<NN / 4, 256, 0, stream>>>(feat, p0W, p0b, (float*)zh);
    k_mmax256h<16, 8><<<(NN / 16) * 8, 256, 0, stream>>>(mb, zh, pmh);
    k_gemm_mrgh<256, 128, 8, 4, 1><<<NN / 4, 128, 0, stream>>>(pmh, (size_t)NN * 128, l0W, l0b, b0, hs);

    // --- GraphSAGE layer 1 (128 -> 128) ---
    k_gemm_ab<128, 128, 4, 1><<<NN / 4, 128, 0, stream>>>(hs, p1W, p1b, (float*)zh);
    k_mmax128h<16, 8><<<(NN / 16) * 8, 256, 0, stream>>>(mb, zh, pmh);
    k_gemm_mrgh<128, 128, 8, 4, 1><<<NN / 4, 128, 0, stream>>>(pmh, (size_t)NN * 64, l1W, l1b, b1, tmp);

    // --- GraphSAGE layer 2 (128 -> 32) ---
    k_gemm_ab<128, 128, 4, 1><<<NN / 4, 128, 0, stream>>>(tmp, p2W, p2b, (float*)zh);
    k_mmax128h<16, 8><<<(NN / 16) * 8, 256, 0, stream>>>(mb, zh, pmh);
    k_gemm_final<8><<<NN / 4, 128, 0, stream>>>(pmh, (size_t)NN * 64, l2W, l2b, b2, out);
}

// Round 20
// 558.864 us; speedup vs baseline: 1.3918x; 1.0321x over previous
//
#include <hip/hip_runtime.h>
#include <hip/hip_fp16.h>
#include <cstdint>
#include <cstddef>

#define NN 4096
#define EE 131072
#define TS 64

__device__ __forceinline__ unsigned fkey(float f) {
    unsigned u = __float_as_uint(f);
    return (u & 0x80000000u) ? ~u : (u | 0x80000000u);
}
__device__ __forceinline__ float funkey(unsigned k) {
    unsigned u = (k & 0x80000000u) ? (k & 0x7fffffffu) : ~k;
    return __uint_as_float(u);
}

// ---- asm pins ----
// packed-half max (VALU, proven safe rounds 14-19)
__device__ __forceinline__ void pkmax(unsigned& a, unsigned x) {
    asm("v_pk_max_f16 %0, %0, %1" : "+v"(a) : "v"(x));
}
// scalar sext of bit `off` of SGPR-resident word (SALU pipe).
// SCC clobber declared: s_lshl_b32 and s_ashr_i32 both write SCC
// (round-12 crash root cause was the missing clobber).
__device__ __forceinline__ unsigned sext_s(unsigned m, int sh) {
    unsigned t;
    asm("s_lshl_b32 %0, %1, %2\n\ts_ashr_i32 %0, %0, 31"
        : "=s"(t) : "s"(m), "s"(sh) : "scc");
    return t;
}
// v_and dst, s, v  (1 VALU; forces mask into SGPR)
__device__ __forceinline__ unsigned and_sv(unsigned sm, unsigned v) {
    unsigned o;
    asm("v_and_b32 %0, %1, %2" : "=v"(o) : "s"(sm), "v"(v));
    return o;
}
// per-lane 1-bit sext: v_bfe_i32 dst, s, v_off, 1 (1 VALU; proven round 14)
__device__ __forceinline__ unsigned vbfe1(unsigned m, unsigned off) {
    unsigned t;
    asm("v_bfe_i32 %0, %1, %2, 1" : "=v"(t) : "s"(m), "v"(off));
    return t;
}
__device__ __forceinline__ unsigned bit_sext_s(unsigned w, int off) {
    return (unsigned)(((int)(w << (31 - off))) >> 31);
}

__global__ void k_count(const int* __restrict__ src, const int* __restrict__ dst,
                        int* __restrict__ cs, int* __restrict__ cd) {
    int e = blockIdx.x * 256 + threadIdx.x;
    if (e < EE) {
        atomicAdd(&cs[src[e]], 1);
        atomicAdd(&cd[dst[e]], 1);
    }
}

__global__ void k_norm(const int* __restrict__ cs, const int* __restrict__ cd,
                       float* __restrict__ on, float* __restrict__ inn) {
    int i = blockIdx.x * 256 + threadIdx.x;
    if (i < NN) {
        int a = cs[i] > 1 ? cs[i] : 1;
        int b = cd[i] > 1 ? cd[i] : 1;
        on[i]  = 1.0f / sqrtf((float)a);
        inn[i] = 1.0f / sqrtf((float)b);
    }
}

// Exclusive prefix sum of cnt_dst (4096) -> off[0..4096]. One block, 1024 thr.
__global__ void k_prefix(const int* __restrict__ cnt, int* __restrict__ off) {
    __shared__ int ls[1024];
    int t = threadIdx.x;
    int base[4];
    int s = 0;
    #pragma unroll
    for (int k = 0; k < 4; ++k) { base[k] = s; s += cnt[t * 4 + k]; }
    ls[t] = s;
    __syncthreads();
    for (int o = 1; o < 1024; o <<= 1) {
        int v = (t >= o) ? ls[t - o] : 0;
        __syncthreads();
        ls[t] += v;
        __syncthreads();
    }
    int excl = (t == 0) ? 0 : ls[t - 1];
    #pragma unroll
    for (int k = 0; k < 4; ++k) off[t * 4 + k] = excl + base[k];
    if (t == 1023) off[4096] = ls[1023];
}

// Bucket edges by dst: elist[off[d] + cursor[d]++] = src.
__global__ void k_bucket(const int* __restrict__ src, const int* __restrict__ dst,
                         const int* __restrict__ off, int* __restrict__ cursor,
                         int* __restrict__ elist) {
    int e = blockIdx.x * 256 + threadIdx.x;
    if (e < EE) {
        int d = dst[e];
        int pos = atomicAdd(&cursor[d], 1);
        elist[off[d] + pos] = src[e];
    }
}

// CSR gather segment-sum + GCN epilogue.
__global__ void k_gather(const float* __restrict__ t, const int* __restrict__ elist,
                         const int* __restrict__ off, const float* __restrict__ inn,
                         const float* __restrict__ b, float* __restrict__ outp,
                         int do_relu) {
    int d = blockIdx.x;
    int j = threadIdx.x;
    int s0 = off[d], s1 = off[d + 1];
    float a0 = 0.f, a1 = 0.f, a2 = 0.f, a3 = 0.f;
    int e = s0;
    for (; e + 4 <= s1; e += 4) {
        a0 += t[(size_t)elist[e + 0] * 128 + j];
        a1 += t[(size_t)elist[e + 1] * 128 + j];
        a2 += t[(size_t)elist[e + 2] * 128 + j];
        a3 += t[(size_t)elist[e + 3] * 128 + j];
    }
    for (; e < s1; ++e) a0 += t[(size_t)elist[e] * 128 + j];
    float v = ((a0 + a1) + (a2 + a3)) * inn[d] + b[j];
    if (do_relu) v = fmaxf(v, 0.0f);
    outp[(size_t)d * 128 + j] = v;
}

// RB rows per block: W[k][j] read once per block for RB rows.
template<int K, int ND, int RB>
__global__ void k_gemm_scale(const float* __restrict__ X, const float* __restrict__ W,
                             const float* __restrict__ scale, float* __restrict__ out) {
    __shared__ float xr[RB][K];
    int i0 = blockIdx.x * RB;
    for (int t = threadIdx.x; t < RB * K; t += ND)
        xr[t / K][t % K] = X[(size_t)(i0 + t / K) * K + t % K];
    __syncthreads();
    int j = threadIdx.x;
    float acc[RB];
    #pragma unroll
    for (int r = 0; r < RB; ++r) acc[r] = 0.0f;
    #pragma unroll 4
    for (int k = 0; k < K; ++k) {
        float w = W[k * ND + j];
        #pragma unroll
        for (int r = 0; r < RB; ++r) acc[r] = fmaf(xr[r][k], w, acc[r]);
    }
    #pragma unroll
    for (int r = 0; r < RB; ++r)
        out[(size_t)(i0 + r) * ND + j] = acc[r] * scale[i0 + r];
}

// f32-input GEMM, RB rows/block. H16=1: relu + packed-half2 output.
template<int K, int ND, int RB, int H16>
__global__ void k_gemm_ab(const float* __restrict__ X, const float* __restrict__ W,
                          const float* __restrict__ b1, float* __restrict__ out) {
    __shared__ float xr[RB][K];
    int i0 = blockIdx.x * RB;
    for (int t = threadIdx.x; t < RB * K; t += ND)
        xr[t / K][t % K] = X[(size_t)(i0 + t / K) * K + t % K];
    __syncthreads();
    int j = threadIdx.x;
    float acc[RB];
    #pragma unroll
    for (int r = 0; r < RB; ++r) acc[r] = 0.0f;
    #pragma unroll 4
    for (int k = 0; k < K; ++k) {
        float w = W[k * ND + j];
        #pragma unroll
        for (int r = 0; r < RB; ++r) acc[r] = fmaf(xr[r][k], w, acc[r]);
    }
    if constexpr (H16) {
        unsigned* oh = (unsigned*)out;
        #pragma unroll
        for (int r = 0; r < RB; ++r) {
            float v = fmaxf(acc[r] + b1[j], 0.0f);
            float o2 = __shfl_xor(v, 1, 64);
            if ((j & 1) == 0) {
                __half2 h = __floats2half2_rn(v, o2);
                oh[(size_t)(i0 + r) * (ND / 2) + (j >> 1)] = *(unsigned*)&h;
            }
        }
    } else {
        #pragma unroll
        for (int r = 0; r < RB; ++r)
            out[(size_t)(i0 + r) * ND + j] = acc[r] + b1[j];
    }
}

// Merge GEMM from NS fp16-packed partials (packed pkmax merge, lossless),
// then f32 GEMM. L2N=1: fused relu + l2-normalize epilogue.
template<int K, int ND, int NS, int RB, int L2N>
__global__ void k_gemm_mrgh(const unsigned* __restrict__ Xh, size_t xstride,
                            const float* __restrict__ W,
                            const float* __restrict__ b1, const float* __restrict__ b2,
                            float* __restrict__ out) {
    __shared__ float xr[RB][K];
    int i0 = blockIdx.x * RB;
    for (int t = threadIdx.x; t < RB * (K / 2); t += ND) {
        int r = t / (K / 2), c = t % (K / 2);
        size_t off = (size_t)(i0 + r) * (K / 2) + c;
        unsigned v = Xh[off];
        #pragma unroll
        for (int s = 1; s < NS; ++s) pkmax(v, Xh[(size_t)s * xstride + off]);
        __half2 h = *(__half2*)&v;
        float2 f = __half22float2(h);
        xr[r][2 * c] = f.x;
        xr[r][2 * c + 1] = f.y;
    }
    __syncthreads();
    int j = threadIdx.x;
    float acc[RB];
    #pragma unroll
    for (int r = 0; r < RB; ++r) acc[r] = 0.0f;
    #pragma unroll 4
    for (int k = 0; k < K; ++k) {
        float w = W[k * ND + j];
        #pragma unroll
        for (int r = 0; r < RB; ++r) acc[r] = fmaf(xr[r][k], w, acc[r]);
    }
    if constexpr (L2N) {
        float v[RB], ss[RB];
        #pragma unroll
        for (int r = 0; r < RB; ++r) {
            float t = acc[r] + b1[j];
            if (b2) t += b2[j];
            v[r] = fmaxf(t, 0.0f);
            ss[r] = v[r] * v[r];
        }
        #pragma unroll
        for (int o = 1; o < 64; o <<= 1)
            #pragma unroll
            for (int r = 0; r < RB; ++r) ss[r] += __shfl_xor(ss[r], o, 64);
        __shared__ float sred[RB][2];
        if ((threadIdx.x & 63) == 0)
            #pragma unroll
            for (int r = 0; r < RB; ++r) sred[r][threadIdx.x >> 6] = ss[r];
        __syncthreads();
        #pragma unroll
        for (int r = 0; r < RB; ++r) {
            float tot = sred[r][0] + sred[r][1];
            out[(size_t)(i0 + r) * ND + j] = v[r] / fmaxf(sqrtf(tot), 1e-12f);
        }
    } else {
        #pragma unroll
        for (int r = 0; r < RB; ++r) {
            float v = acc[r] + b1[j];
            if (b2) v += b2[j];
            out[(size_t)(i0 + r) * ND + j] = v;
        }
    }
}

// ---- S = h h^T 64x64 tile; MODE 0: max-only; MODE 1: recompute + bit-emit ----
template<int MODE>
__global__ __launch_bounds__(256, 4) void k_stile(const float* __restrict__ h,
                                                  const float* __restrict__ u,
                                                  unsigned* __restrict__ smax_key,
                                                  unsigned* __restrict__ mb) {
    int ti = blockIdx.y, tj = blockIdx.x;
    if (tj < ti) return;
    __shared__ float Ah[TS][68];
    __shared__ float Bh[TS][68];
    int tid = threadIdx.x;
    int tx = tid & 15, ty = tid >> 4;
    const float* ha = h + (size_t)ti * TS * 128;
    const float* hb = h + (size_t)tj * TS * 128;

    float acc[4][4];
    #pragma unroll
    for (int r = 0; r < 4; ++r)
        #pragma unroll
        for (int c = 0; c < 4; ++c) acc[r][c] = 0.0f;

    for (int half = 0; half < 2; ++half) {
        __syncthreads();
        #pragma unroll
        for (int t = 0; t < 4; ++t) {
            int f = tid + t * 256;
            int row = f >> 4, kk = f & 15;
            *(float4*)&Ah[row][kk * 4] = *(const float4*)(ha + (size_t)row * 128 + half * 64 + kk * 4);
            *(float4*)&Bh[row][kk * 4] = *(const float4*)(hb + (size_t)row * 128 + half * 64 + kk * 4);
        }
        __syncthreads();
        #pragma unroll 2
        for (int k4 = 0; k4 < 16; ++k4) {
            float4 a[4], b[4];
            #pragma unroll
            for (int r = 0; r < 4; ++r) a[r] = *(const float4*)&Ah[ty + 16 * r][k4 * 4];
            #pragma unroll
            for (int c = 0; c < 4; ++c) b[c] = *(const float4*)&Bh[tx + 16 * c][k4 * 4];
            #pragma unroll
            for (int r = 0; r < 4; ++r)
                #pragma unroll
                for (int c = 0; c < 4; ++c) {
                    acc[r][c] = fmaf(a[r].x, b[c].x, acc[r][c]);
                    acc[r][c] = fmaf(a[r].y, b[c].y, acc[r][c]);
                    acc[r][c] = fmaf(a[r].z, b[c].z, acc[r][c]);
                    acc[r][c] = fmaf(a[r].w, b[c].w, acc[r][c]);
                }
        }
    }

    if constexpr (MODE == 0) {
        float m = -3.4e38f;
        #pragma unroll
        for (int r = 0; r < 4; ++r)
            #pragma unroll
            for (int c = 0; c < 4; ++c) m = fmaxf(m, acc[r][c]);
        #pragma unroll
        for (int o = 1; o < 64; o <<= 1) m = fmaxf(m, __shfl_xor(m, o, 64));
        __shared__ float wm[4];
        if ((tid & 63) == 0) wm[tid >> 6] = m;
        __syncthreads();
        if (tid == 0) {
            float mm = fmaxf(fmaxf(wm[0], wm[1]), fmaxf(wm[2], wm[3]));
            atomicMax(smax_key, fkey(mm));
        }
    } else {
        float smax = funkey(*smax_key);
        float epmax = 1.0f / (1.0f + expf(-smax));
        __shared__ unsigned lm[TS][2];
        __shared__ unsigned lmT[TS][2];
        if (tid < 128) { lm[tid >> 1][tid & 1] = 0u; lmT[tid >> 1][tid & 1] = 0u; }
        __syncthreads();
        #pragma unroll
        for (int r = 0; r < 4; ++r) {
            #pragma unroll
            for (int c = 0; c < 4; ++c) {
                int li = ty + 16 * r, lj = tx + 16 * c;
                int gi = ti * TS + li, gj = tj * TS + lj;
                bool bit = false;
                if (gi < gj) {
                    float ep = 1.0f / (1.0f + expf(-acc[r][c]));
                    float P = ep / epmax;
                    float Pc = fminf(fmaxf(P, 1e-6f), 1.0f - 1e-6f);
                    float uu = u[(size_t)gi * NN + gj];
                    float ucv = fminf(fmaxf(uu, 1e-6f), 1.0f - 1e-6f);
                    bit = Pc > (1.0f - ucv);
                } else if (gi == gj) {
                    bit = true;
                }
                if (bit) {
                    atomicOr(&lm[li][lj >> 5], 1u << (lj & 31));
                    atomicOr(&lmT[lj][li >> 5], 1u << (li & 31));
                }
            }
        }
        __syncthreads();
        if (tid < 128) {
            int r = tid >> 1, wq = tid & 1;
            unsigned word = lm[r][wq];
            if (ti == tj) word |= lmT[r][wq];
            mb[(size_t)(ti * TS + r) * 128 + tj * 2 + wq] = word;
        } else if (ti != tj) {
            int r = (tid - 128) >> 1, wq = tid & 1;
            mb[(size_t)(tj * TS + r) * 128 + ti * 2 + wq] = lmT[r][wq];
        }
    }
}

// Pass 1 (S-store path): compute tile, store S to ws, fold into global max.
__global__ __launch_bounds__(256, 4) void k_stile_store(const float* __restrict__ h,
                                                        float* __restrict__ S,
                                                        unsigned* __restrict__ smax_key) {
    int ti = blockIdx.y, tj = blockIdx.x;
    if (tj < ti) return;
    __shared__ float Ah[TS][68];
    __shared__ float Bh[TS][68];
    int tid = threadIdx.x;
    int tx = tid & 15, ty = tid >> 4;
    const float* ha = h + (size_t)ti * TS * 128;
    const float* hb = h + (size_t)tj * TS * 128;

    float acc[4][4];
    #pragma unroll
    for (int r = 0; r < 4; ++r)
        #pragma unroll
        for (int c = 0; c < 4; ++c) acc[r][c] = 0.0f;

    for (int half = 0; half < 2; ++half) {
        __syncthreads();
        #pragma unroll
        for (int t = 0; t < 4; ++t) {
            int f = tid + t * 256;
            int row = f >> 4, kk = f & 15;
            *(float4*)&Ah[row][kk * 4] = *(const float4*)(ha + (size_t)row * 128 + half * 64 + kk * 4);
            *(float4*)&Bh[row][kk * 4] = *(const float4*)(hb + (size_t)row * 128 + half * 64 + kk * 4);
        }
        __syncthreads();
        #pragma unroll 2
        for (int k4 = 0; k4 < 16; ++k4) {
            float4 a[4], b[4];
            #pragma unroll
            for (int r = 0; r < 4; ++r) a[r] = *(const float4*)&Ah[ty + 16 * r][k4 * 4];
            #pragma unroll
            for (int c = 0; c < 4; ++c) b[c] = *(const float4*)&Bh[tx + 16 * c][k4 * 4];
            #pragma unroll
            for (int r = 0; r < 4; ++r)
                #pragma unroll
                for (int c = 0; c < 4; ++c) {
                    acc[r][c] = fmaf(a[r].x, b[c].x, acc[r][c]);
                    acc[r][c] = fmaf(a[r].y, b[c].y, acc[r][c]);
                    acc[r][c] = fmaf(a[r].z, b[c].z, acc[r][c]);
                    acc[r][c] = fmaf(a[r].w, b[c].w, acc[r][c]);
                }
        }
    }

    float* sp = S + (size_t)(ti * 64 + tj) * 4096;
    #pragma unroll
    for (int r = 0; r < 4; ++r)
        #pragma unroll
        for (int c = 0; c < 4; ++c)
            sp[(ty + 16 * r) * 64 + tx + 16 * c] = acc[r][c];

    float m = -3.4e38f;
    #pragma unroll
    for (int r = 0; r < 4; ++r)
        #pragma unroll
        for (int c = 0; c < 4; ++c) m = fmaxf(m, acc[r][c]);
    #pragma unroll
    for (int o = 1; o < 64; o <<= 1) m = fmaxf(m, __shfl_xor(m, o, 64));
    __shared__ float wm[4];
    if ((tid & 63) == 0) wm[tid >> 6] = m;
    __syncthreads();
    if (tid == 0)
        atomicMax(smax_key, fkey(fmaxf(fmaxf(wm[0], wm[1]), fmaxf(wm[2], wm[3]))));
}

// Pass 2 (S-store path): read stored S, emit mask bits.
__global__ __launch_bounds__(256, 4) void k_bitemit(const float* __restrict__ S,
                                                    const float* __restrict__ u,
                                                    const unsigned* __restrict__ smax_key,
                                                    unsigned* __restrict__ mb) {
    int ti = blockIdx.y, tj = blockIdx.x;
    if (tj < ti) return;
    int tid = threadIdx.x;
    int tx = tid & 15, ty = tid >> 4;
    float smax = funkey(*smax_key);
    float epmax = 1.0f / (1.0f + expf(-smax));
    __shared__ unsigned lm[TS][2];
    __shared__ unsigned lmT[TS][2];
    if (tid < 128) { lm[tid >> 1][tid & 1] = 0u; lmT[tid >> 1][tid & 1] = 0u; }
    __syncthreads();
    const float* sp = S + (size_t)(ti * 64 + tj) * 4096;
    #pragma unroll
    for (int r = 0; r < 4; ++r) {
        #pragma unroll
        for (int c = 0; c < 4; ++c) {
            int li = ty + 16 * r, lj = tx + 16 * c;
            int gi = ti * TS + li, gj = tj * TS + lj;
            bool bit = false;
            if (gi < gj) {
                float ep = 1.0f / (1.0f + expf(-sp[li * 64 + lj]));
                float P = ep / epmax;
                float Pc = fminf(fmaxf(P, 1e-6f), 1.0f - 1e-6f);
                float uu = u[(size_t)gi * NN + gj];
                float ucv = fminf(fmaxf(uu, 1e-6f), 1.0f - 1e-6f);
                bit = Pc > (1.0f - ucv);
            } else if (gi == gj) {
                bit = true;
            }
            if (bit) {
                atomicOr(&lm[li][lj >> 5], 1u << (lj & 31));
                atomicOr(&lmT[lj][li >> 5], 1u << (li & 31));
            }
        }
    }
    __syncthreads();
    if (tid < 128) {
        int r = tid >> 1, wq = tid & 1;
        unsigned word = lm[r][wq];
        if (ti == tj) word |= lmT[r][wq];
        mb[(size_t)(ti * TS + r) * 128 + tj * 2 + wq] = word;
    } else if (ti != tj) {
        int r = (tid - 128) >> 1, wq = tid & 1;
        mb[(size_t)(tj * TS + r) * 128 + ti * 2 + wq] = lmT[r][wq];
    }
}

// Masked max, D=256, fp16-packed z; fp16-packed partial output.
// Mask word -> SGPR; bit sext on SALU (scc clobbered); v_and(s,v) + pk_max:
// exactly 4 VALU per (row,j) pair.
template<int RT, int JS>
__global__ __launch_bounds__(256, 8) void k_mmax256h(const unsigned* __restrict__ mb,
                                                     const unsigned* __restrict__ zh,
                                                     unsigned* __restrict__ pmh) {
    constexpr int JPS = NN / JS;   // 512
    constexpr int WPS = JPS / 32;  // 16
    constexpr int RPG = RT / 4;    // 4
    constexpr int NRB = NN / RT;   // 256
    int rowblk = blockIdx.x % NRB, js = blockIdx.x / NRB;
    int i0 = rowblk * RT;

    __shared__ unsigned msk[RT][WPS + 1];
    {
        int t = threadIdx.x;           // RT*WPS == 256
        msk[t / WPS][t % WPS] = mb[(size_t)(i0 + t / WPS) * 128 + js * WPS + t % WPS];
    }
    __syncthreads();

    int d = threadIdx.x & 63;
    int g = threadIdx.x >> 6;
    const uint2* zbase = (const uint2*)zh + (size_t)js * JPS * 64 + d;   // row = 64 uint2

    uint2 acc[RPG];
    #pragma unroll
    for (int r = 0; r < RPG; ++r) acc[r] = make_uint2(0u, 0u);

    #pragma unroll 1
    for (int wq = 0; wq < WPS; ++wq) {
        unsigned m[RPG];
        #pragma unroll
        for (int r = 0; r < RPG; ++r)
            m[r] = (unsigned)__builtin_amdgcn_readfirstlane((int)msk[g * RPG + r][wq]);
        const uint2* zp = zbase + (size_t)(wq * 32) * 64;
        #pragma unroll 2
        for (int j4 = 0; j4 < 32; j4 += 4) {
            uint2 z0 = zp[0 * 64];
            uint2 z1 = zp[1 * 64];
            uint2 z2 = zp[2 * 64];
            uint2 z3 = zp[3 * 64];
            #pragma unroll
            for (int r = 0; r < RPG; ++r) {
                unsigned s0 = sext_s(m[r], 31 - (j4 + 0));
                unsigned s1 = sext_s(m[r], 31 - (j4 + 1));
                unsigned s2 = sext_s(m[r], 31 - (j4 + 2));
                unsigned s3 = sext_s(m[r], 31 - (j4 + 3));
                pkmax(acc[r].x, and_sv(s0, z0.x)); pkmax(acc[r].y, and_sv(s0, z0.y));
                pkmax(acc[r].x, and_sv(s1, z1.x)); pkmax(acc[r].y, and_sv(s1, z1.y));
                pkmax(acc[r].x, and_sv(s2, z2.x)); pkmax(acc[r].y, and_sv(s2, z2.y));
                pkmax(acc[r].x, and_sv(s3, z3.x)); pkmax(acc[r].y, and_sv(s3, z3.y));
            }
            zp += 4 * 64;
        }
    }

    uint2* po = (uint2*)(pmh + (size_t)js * NN * 128);   // row = 128 u32 = 64 uint2
    #pragma unroll
    for (int r = 0; r < RPG; ++r)
        po[(size_t)(i0 + g * RPG + r) * 64 + d] = acc[r];
}

// Masked max, D=128, fp16-packed z; fp16-packed partial output.
// Lane-dependent bit offset (jpar) -> single v_bfe_i32 per (row, j-step).
template<int RT, int JS>
__global__ __launch_bounds__(256, 8) void k_mmax128h(const unsigned* __restrict__ mb,
                                                     const unsigned* __restrict__ zh,
                                                     unsigned* __restrict__ pmh) {
    constexpr int JPS = NN / JS;   // 512
    constexpr int WPS = JPS / 32;  // 16
    constexpr int RPG = RT / 4;    // 4
    constexpr int NRB = NN / RT;   // 256
    int rowblk = blockIdx.x % NRB, js = blockIdx.x / NRB;
    int i0 = rowblk * RT;

    __shared__ unsigned msk[RT][WPS + 1];
    {
        int t = threadIdx.x;
        msk[t / WPS][t % WPS] = mb[(size_t)(i0 + t / WPS) * 128 + js * WPS + t % WPS];
    }
    __syncthreads();

    int lane = threadIdx.x & 63;
    int g = threadIdx.x >> 6;
    unsigned jpar = lane >> 5;
    int d2 = lane & 31;                 // uint2 index within row (32 uint2 = 64 u32)
    const uint2* zbase = (const uint2*)zh + (size_t)js * JPS * 32 + d2;

    uint2 acc[RPG];
    #pragma unroll
    for (int r = 0; r < RPG; ++r) acc[r] = make_uint2(0u, 0u);

    #pragma unroll 1
    for (int wq = 0; wq < WPS; ++wq) {
        unsigned m[RPG];
        #pragma unroll
        for (int r = 0; r < RPG; ++r)
            m[r] = (unsigned)__builtin_amdgcn_readfirstlane((int)msk[g * RPG + r][wq]);
        const uint2* zp = zbase + (size_t)(wq * 32) * 32;
        #pragma unroll 2
        for (int j4 = 0; j4 < 32; j4 += 4) {
            uint2 za = zp[(size_t)jpar * 32];
            uint2 zb = zp[(size_t)(2 + jpar) * 32];
            unsigned oa = (unsigned)j4 + jpar, ob = (unsigned)j4 + 2 + jpar;
            #pragma unroll
            for (int r = 0; r < RPG; ++r) {
                unsigned sa = vbfe1(m[r], oa);
                unsigned sb = vbfe1(m[r], ob);
                pkmax(acc[r].x, sa & za.x); pkmax(acc[r].y, sa & za.y);
                pkmax(acc[r].x, sb & zb.x); pkmax(acc[r].y, sb & zb.y);
            }
            zp += 4 * 32;
        }
    }

    #pragma unroll
    for (int r = 0; r < RPG; ++r) {
        unsigned ox = __shfl_xor(acc[r].x, 32, 64);
        unsigned oy = __shfl_xor(acc[r].y, 32, 64);
        pkmax(acc[r].x, ox);
        pkmax(acc[r].y, oy);
    }
    if (!jpar) {
        uint2* po = (uint2*)(pmh + (size_t)js * NN * 64);   // row = 64 u32 = 32 uint2
        #pragma unroll
        for (int r = 0; r < RPG; ++r)
            po[(size_t)(i0 + g * RPG + r) * 32 + d2] = acc[r];
    }
}

// Final 128->32 GEMM, NS fp16-packed partials, LDS-staged, 4 rows per block.
template<int NS>
__global__ void k_gemm_final(const unsigned* __restrict__ Xh, size_t xstride,
                             const float* __restrict__ W,
                             const float* __restrict__ b1, const float* __restrict__ b2,
                             float* __restrict__ out) {
    __shared__ float xr[4][128];
    int i0 = blockIdx.x * 4;
    for (int t = threadIdx.x; t < 256; t += 128) {
        int r = t >> 6, c = t & 63;
        size_t off = (size_t)(i0 + r) * 64 + c;
        unsigned v = Xh[off];
        #pragma unroll
        for (int s = 1; s < NS; ++s) pkmax(v, Xh[(size_t)s * xstride + off]);
        __half2 h = *(__half2*)&v;
        float2 f = __half22float2(h);
        xr[r][2 * c] = f.x;
        xr[r][2 * c + 1] = f.y;
    }
    __syncthreads();
    int il = threadIdx.x >> 5, j = threadIdx.x & 31;
    float acc = 0.0f;
    #pragma unroll 8
    for (int k = 0; k < 128; ++k) acc = fmaf(xr[il][k], W[k * 32 + j], acc);
    out[(size_t)(i0 + il) * 32 + j] = acc + b1[j] + b2[j];
}

extern "C" void kernel_launch(void* const* d_in, const int* in_sizes, int n_in,
                              void* d_out, int out_size, void* d_ws, size_t ws_size,
                              hipStream_t stream) {
    const float* inputs = (const float*)d_in[1];
    const float* feat   = (const float*)d_in[2];
    const float* u      = (const float*)d_in[3];
    const int*   src    = (const int*)d_in[4];
    const int*   dst    = (const int*)d_in[5];
    const float* gc0W = (const float*)d_in[6],  *gc0b = (const float*)d_in[7];
    const float* gc1W = (const float*)d_in[8],  *gc1b = (const float*)d_in[9];
    const float* p0W  = (const float*)d_in[10], *p0b  = (const float*)d_in[11];
    const float* l0W  = (const float*)d_in[12], *l0b  = (const float*)d_in[13];
    const float* b0   = (const float*)d_in[14];
    const float* p1W  = (const float*)d_in[15], *p1b  = (const float*)d_in[16];
    const float* l1W  = (const float*)d_in[17], *l1b  = (const float*)d_in[18];
    const float* b1   = (const float*)d_in[19];
    const float* p2W  = (const float*)d_in[20], *p2b  = (const float*)d_in[21];
    const float* l2W  = (const float*)d_in[22], *l2b  = (const float*)d_in[23];
    const float* b2   = (const float*)d_in[24];
    float* out = (float*)d_out;

    const size_t MB = 1048576;
    char* w = (char*)d_ws;
    int*      cnt_src  = (int*)(w + 0);            // 16 KB
    int*      cnt_dst  = (int*)(w + 16384);        // 16 KB
    float*    on       = (float*)(w + 32768);      // 16 KB
    float*    inn      = (float*)(w + 49152);      // 16 KB
    unsigned* smax_key = (unsigned*)(w + 65536);   // 4 B (padded)
    int*      cursor   = (int*)(w + 81920);        // 16 KB
    int*      eoff     = (int*)(w + 98304);        // 16.4 KB (4097 ints)
    char*     big      = w + 131072;
    float*    tmp      = (float*)(big);            // 2 MB
    int*      elist    = (int*)(big + 2 * MB);     // 512 KB
    float*    hbuf     = (float*)(big + 4 * MB);   // 2 MB
    unsigned* mb       = (unsigned*)(big + 6 * MB);// 2 MB
    unsigned* zh       = (unsigned*)(big + 8 * MB);// 2 MB (fp16-packed z)
    unsigned* pmh      = (unsigned*)(big + 12 * MB);// 16 MB (8 fp16 split partials)
    float*    hs       = (float*)(big + 44 * MB);  // 2 MB
    float*    Sbuf     = (float*)(big + 46 * MB);  // 64 MB
    bool use_sstore = ws_size >= 131072 + 110 * MB;

    hipMemsetAsync(w, 0, 131072, stream);
    k_count<<<EE / 256, 256, 0, stream>>>(src, dst, cnt_src, cnt_dst);
    k_norm<<<NN / 256, 256, 0, stream>>>(cnt_src, cnt_dst, on, inn);
    k_prefix<<<1, 1024, 0, stream>>>(cnt_dst, eoff);
    k_bucket<<<EE / 256, 256, 0, stream>>>(src, dst, eoff, cursor, elist);

    // --- GCN layer 0 ---
    k_gemm_scale<256, 128, 4><<<NN / 4, 128, 0, stream>>>(inputs, gc0W, on, tmp);
    k_gather<<<NN, 128, 0, stream>>>(tmp, elist, eoff, inn, gc0b, hbuf, 1);

    // --- GCN layer 1 ---
    k_gemm_scale<128, 128, 4><<<NN / 4, 128, 0, stream>>>(hbuf, gc1W, on, tmp);
    k_gather<<<NN, 128, 0, stream>>>(tmp, elist, eoff, inn, gc1b, hbuf, 0);

    // --- decode: S max + mask bits ---
    dim3 tg(64, 64);
    if (use_sstore) {
        k_stile_store<<<tg, 256, 0, stream>>>(hbuf, Sbuf, smax_key);
        k_bitemit<<<tg, 256, 0, stream>>>(Sbuf, u, smax_key, mb);
    } else {
        k_stile<0><<<tg, 256, 0, stream>>>(hbuf, nullptr, smax_key, nullptr);
        k_stile<1><<<tg, 256, 0, stream>>>(hbuf, u, smax_key, mb);
    }

    // --- GraphSAGE layer 0 (256 -> 128), fp16 masked max + fp16 partials ---
    k_gemm_ab<256, 256, 4, 1><<<NN / 4, 256, 0, stream>>>(feat, p0W, p0b, (float*)zh);
    k_mmax256h<16, 8><<<(NN / 16) * 8, 256, 0, stream>>>(mb, zh, pmh);
    k_gemm_mrgh<256, 128, 8, 4, 1><<<NN / 4, 128, 0, stream>>>(pmh, (size_t)NN * 128, l0W, l0b, b0, hs);

    // --- GraphSAGE layer 1 (128 -> 128) ---
    k_gemm_ab<128, 128, 4, 1><<<NN / 4, 128, 0, stream>>>(hs, p1W, p1b, (float*)zh);
    k_mmax128h<16, 8><<<(NN / 16) * 8, 256, 0, stream>>>(mb, zh, pmh);
    k_gemm_mrgh<128, 128, 8, 4, 1><<<NN / 4, 128, 0, stream>>>(pmh, (size_t)NN * 64, l1W, l1b, b1, tmp);

    // --- GraphSAGE layer 2 (128 -> 32) ---
    k_gemm_ab<128, 128, 4, 1><<<NN / 4, 128, 0, stream>>>(tmp, p2W, p2b, (float*)zh);
    k_mmax128h<16, 8><<<(NN / 16) * 8, 256, 0, stream>>>(mb, zh, pmh);
    k_gemm_final<8><<<NN / 4, 128, 0, stream>>>(pmh, (size_t)NN * 64, l2W, l2b, b2, out);
}

// Round 21
// 546.720 us; speedup vs baseline: 1.4227x; 1.0222x over previous
//
#include <hip/hip_runtime.h>
#include <hip/hip_fp16.h>
#include <cstdint>
#include <cstddef>

#define NN 4096
#define EE 131072
#define TS 64

__device__ __forceinline__ unsigned fkey(float f) {
    unsigned u = __float_as_uint(f);
    return (u & 0x80000000u) ? ~u : (u | 0x80000000u);
}
__device__ __forceinline__ float funkey(unsigned k) {
    unsigned u = (k & 0x80000000u) ? (k & 0x7fffffffu) : ~k;
    return __uint_as_float(u);
}

// ---- asm pins (VALU-only; proven safe rounds 14-20) ----
__device__ __forceinline__ void pkmax(unsigned& a, unsigned x) {
    asm("v_pk_max_f16 %0, %0, %1" : "+v"(a) : "v"(x));
}
// per-lane 1-bit sext: v_bfe_i32 dst, s, v_off, 1 (proven round 20: -10us each mmax128h)
__device__ __forceinline__ unsigned vbfe1(unsigned m, unsigned off) {
    unsigned t;
    asm("v_bfe_i32 %0, %1, %2, 1" : "=v"(t) : "s"(m), "v"(off));
    return t;
}
// C++ sext (round-19 form: fastest of six mmax256h variants)
__device__ __forceinline__ unsigned bit_sext_s(unsigned w, int off) {
    return (unsigned)(((int)(w << (31 - off))) >> 31);
}

__global__ void k_count(const int* __restrict__ src, const int* __restrict__ dst,
                        int* __restrict__ cs, int* __restrict__ cd) {
    int e = blockIdx.x * 256 + threadIdx.x;
    if (e < EE) {
        atomicAdd(&cs[src[e]], 1);
        atomicAdd(&cd[dst[e]], 1);
    }
}

__global__ void k_norm(const int* __restrict__ cs, const int* __restrict__ cd,
                       float* __restrict__ on, float* __restrict__ inn) {
    int i = blockIdx.x * 256 + threadIdx.x;
    if (i < NN) {
        int a = cs[i] > 1 ? cs[i] : 1;
        int b = cd[i] > 1 ? cd[i] : 1;
        on[i]  = 1.0f / sqrtf((float)a);
        inn[i] = 1.0f / sqrtf((float)b);
    }
}

// Exclusive prefix sum of cnt_dst (4096) -> off[0..4096]. One block, 1024 thr.
__global__ void k_prefix(const int* __restrict__ cnt, int* __restrict__ off) {
    __shared__ int ls[1024];
    int t = threadIdx.x;
    int base[4];
    int s = 0;
    #pragma unroll
    for (int k = 0; k < 4; ++k) { base[k] = s; s += cnt[t * 4 + k]; }
    ls[t] = s;
    __syncthreads();
    for (int o = 1; o < 1024; o <<= 1) {
        int v = (t >= o) ? ls[t - o] : 0;
        __syncthreads();
        ls[t] += v;
        __syncthreads();
    }
    int excl = (t == 0) ? 0 : ls[t - 1];
    #pragma unroll
    for (int k = 0; k < 4; ++k) off[t * 4 + k] = excl + base[k];
    if (t == 1023) off[4096] = ls[1023];
}

// Bucket edges by dst: elist[off[d] + cursor[d]++] = src.
__global__ void k_bucket(const int* __restrict__ src, const int* __restrict__ dst,
                         const int* __restrict__ off, int* __restrict__ cursor,
                         int* __restrict__ elist) {
    int e = blockIdx.x * 256 + threadIdx.x;
    if (e < EE) {
        int d = dst[e];
        int pos = atomicAdd(&cursor[d], 1);
        elist[off[d] + pos] = src[e];
    }
}

// CSR gather segment-sum + GCN epilogue.
__global__ void k_gather(const float* __restrict__ t, const int* __restrict__ elist,
                         const int* __restrict__ off, const float* __restrict__ inn,
                         const float* __restrict__ b, float* __restrict__ outp,
                         int do_relu) {
    int d = blockIdx.x;
    int j = threadIdx.x;
    int s0 = off[d], s1 = off[d + 1];
    float a0 = 0.f, a1 = 0.f, a2 = 0.f, a3 = 0.f;
    int e = s0;
    for (; e + 4 <= s1; e += 4) {
        a0 += t[(size_t)elist[e + 0] * 128 + j];
        a1 += t[(size_t)elist[e + 1] * 128 + j];
        a2 += t[(size_t)elist[e + 2] * 128 + j];
        a3 += t[(size_t)elist[e + 3] * 128 + j];
    }
    for (; e < s1; ++e) a0 += t[(size_t)elist[e] * 128 + j];
    float v = ((a0 + a1) + (a2 + a3)) * inn[d] + b[j];
    if (do_relu) v = fmaxf(v, 0.0f);
    outp[(size_t)d * 128 + j] = v;
}

// RB rows per block: W[k][j] read once per block for RB rows.
template<int K, int ND, int RB>
__global__ void k_gemm_scale(const float* __restrict__ X, const float* __restrict__ W,
                             const float* __restrict__ scale, float* __restrict__ out) {
    __shared__ float xr[RB][K];
    int i0 = blockIdx.x * RB;
    for (int t = threadIdx.x; t < RB * K; t += ND)
        xr[t / K][t % K] = X[(size_t)(i0 + t / K) * K + t % K];
    __syncthreads();
    int j = threadIdx.x;
    float acc[RB];
    #pragma unroll
    for (int r = 0; r < RB; ++r) acc[r] = 0.0f;
    #pragma unroll 4
    for (int k = 0; k < K; ++k) {
        float w = W[k * ND + j];
        #pragma unroll
        for (int r = 0; r < RB; ++r) acc[r] = fmaf(xr[r][k], w, acc[r]);
    }
    #pragma unroll
    for (int r = 0; r < RB; ++r)
        out[(size_t)(i0 + r) * ND + j] = acc[r] * scale[i0 + r];
}

// f32-input GEMM, RB rows/block. H16=1: relu + packed-half2 output.
template<int K, int ND, int RB, int H16>
__global__ void k_gemm_ab(const float* __restrict__ X, const float* __restrict__ W,
                          const float* __restrict__ b1, float* __restrict__ out) {
    __shared__ float xr[RB][K];
    int i0 = blockIdx.x * RB;
    for (int t = threadIdx.x; t < RB * K; t += ND)
        xr[t / K][t % K] = X[(size_t)(i0 + t / K) * K + t % K];
    __syncthreads();
    int j = threadIdx.x;
    float acc[RB];
    #pragma unroll
    for (int r = 0; r < RB; ++r) acc[r] = 0.0f;
    #pragma unroll 4
    for (int k = 0; k < K; ++k) {
        float w = W[k * ND + j];
        #pragma unroll
        for (int r = 0; r < RB; ++r) acc[r] = fmaf(xr[r][k], w, acc[r]);
    }
    if constexpr (H16) {
        unsigned* oh = (unsigned*)out;
        #pragma unroll
        for (int r = 0; r < RB; ++r) {
            float v = fmaxf(acc[r] + b1[j], 0.0f);
            float o2 = __shfl_xor(v, 1, 64);
            if ((j & 1) == 0) {
                __half2 h = __floats2half2_rn(v, o2);
                oh[(size_t)(i0 + r) * (ND / 2) + (j >> 1)] = *(unsigned*)&h;
            }
        }
    } else {
        #pragma unroll
        for (int r = 0; r < RB; ++r)
            out[(size_t)(i0 + r) * ND + j] = acc[r] + b1[j];
    }
}

// Merge GEMM from NS fp16-packed partials (packed pkmax merge, lossless),
// then f32 GEMM. L2N=1: fused relu + l2-normalize epilogue.
template<int K, int ND, int NS, int RB, int L2N>
__global__ void k_gemm_mrgh(const unsigned* __restrict__ Xh, size_t xstride,
                            const float* __restrict__ W,
                            const float* __restrict__ b1, const float* __restrict__ b2,
                            float* __restrict__ out) {
    __shared__ float xr[RB][K];
    int i0 = blockIdx.x * RB;
    for (int t = threadIdx.x; t < RB * (K / 2); t += ND) {
        int r = t / (K / 2), c = t % (K / 2);
        size_t off = (size_t)(i0 + r) * (K / 2) + c;
        unsigned v = Xh[off];
        #pragma unroll
        for (int s = 1; s < NS; ++s) pkmax(v, Xh[(size_t)s * xstride + off]);
        __half2 h = *(__half2*)&v;
        float2 f = __half22float2(h);
        xr[r][2 * c] = f.x;
        xr[r][2 * c + 1] = f.y;
    }
    __syncthreads();
    int j = threadIdx.x;
    float acc[RB];
    #pragma unroll
    for (int r = 0; r < RB; ++r) acc[r] = 0.0f;
    #pragma unroll 4
    for (int k = 0; k < K; ++k) {
        float w = W[k * ND + j];
        #pragma unroll
        for (int r = 0; r < RB; ++r) acc[r] = fmaf(xr[r][k], w, acc[r]);
    }
    if constexpr (L2N) {
        float v[RB], ss[RB];
        #pragma unroll
        for (int r = 0; r < RB; ++r) {
            float t = acc[r] + b1[j];
            if (b2) t += b2[j];
            v[r] = fmaxf(t, 0.0f);
            ss[r] = v[r] * v[r];
        }
        #pragma unroll
        for (int o = 1; o < 64; o <<= 1)
            #pragma unroll
            for (int r = 0; r < RB; ++r) ss[r] += __shfl_xor(ss[r], o, 64);
        __shared__ float sred[RB][2];
        if ((threadIdx.x & 63) == 0)
            #pragma unroll
            for (int r = 0; r < RB; ++r) sred[r][threadIdx.x >> 6] = ss[r];
        __syncthreads();
        #pragma unroll
        for (int r = 0; r < RB; ++r) {
            float tot = sred[r][0] + sred[r][1];
            out[(size_t)(i0 + r) * ND + j] = v[r] / fmaxf(sqrtf(tot), 1e-12f);
        }
    } else {
        #pragma unroll
        for (int r = 0; r < RB; ++r) {
            float v = acc[r] + b1[j];
            if (b2) v += b2[j];
            out[(size_t)(i0 + r) * ND + j] = v;
        }
    }
}

// ---- S = h h^T 64x64 tile; MODE 0: max-only; MODE 1: recompute + bit-emit ----
template<int MODE>
__global__ __launch_bounds__(256, 4) void k_stile(const float* __restrict__ h,
                                                  const float* __restrict__ u,
                                                  unsigned* __restrict__ smax_key,
                                                  unsigned* __restrict__ mb) {
    int ti = blockIdx.y, tj = blockIdx.x;
    if (tj < ti) return;
    __shared__ float Ah[TS][68];
    __shared__ float Bh[TS][68];
    int tid = threadIdx.x;
    int tx = tid & 15, ty = tid >> 4;
    const float* ha = h + (size_t)ti * TS * 128;
    const float* hb = h + (size_t)tj * TS * 128;

    float acc[4][4];
    #pragma unroll
    for (int r = 0; r < 4; ++r)
        #pragma unroll
        for (int c = 0; c < 4; ++c) acc[r][c] = 0.0f;

    for (int half = 0; half < 2; ++half) {
        __syncthreads();
        #pragma unroll
        for (int t = 0; t < 4; ++t) {
            int f = tid + t * 256;
            int row = f >> 4, kk = f & 15;
            *(float4*)&Ah[row][kk * 4] = *(const float4*)(ha + (size_t)row * 128 + half * 64 + kk * 4);
            *(float4*)&Bh[row][kk * 4] = *(const float4*)(hb + (size_t)row * 128 + half * 64 + kk * 4);
        }
        __syncthreads();
        #pragma unroll 2
        for (int k4 = 0; k4 < 16; ++k4) {
            float4 a[4], b[4];
            #pragma unroll
            for (int r = 0; r < 4; ++r) a[r] = *(const float4*)&Ah[ty + 16 * r][k4 * 4];
            #pragma unroll
            for (int c = 0; c < 4; ++c) b[c] = *(const float4*)&Bh[tx + 16 * c][k4 * 4];
            #pragma unroll
            for (int r = 0; r < 4; ++r)
                #pragma unroll
                for (int c = 0; c < 4; ++c) {
                    acc[r][c] = fmaf(a[r].x, b[c].x, acc[r][c]);
                    acc[r][c] = fmaf(a[r].y, b[c].y, acc[r][c]);
                    acc[r][c] = fmaf(a[r].z, b[c].z, acc[r][c]);
                    acc[r][c] = fmaf(a[r].w, b[c].w, acc[r][c]);
                }
        }
    }

    if constexpr (MODE == 0) {
        float m = -3.4e38f;
        #pragma unroll
        for (int r = 0; r < 4; ++r)
            #pragma unroll
            for (int c = 0; c < 4; ++c) m = fmaxf(m, acc[r][c]);
        #pragma unroll
        for (int o = 1; o < 64; o <<= 1) m = fmaxf(m, __shfl_xor(m, o, 64));
        __shared__ float wm[4];
        if ((tid & 63) == 0) wm[tid >> 6] = m;
        __syncthreads();
        if (tid == 0) {
            float mm = fmaxf(fmaxf(wm[0], wm[1]), fmaxf(wm[2], wm[3]));
            atomicMax(smax_key, fkey(mm));
        }
    } else {
        float smax = funkey(*smax_key);
        float epmax = 1.0f / (1.0f + expf(-smax));
        __shared__ unsigned lm[TS][2];
        __shared__ unsigned lmT[TS][2];
        if (tid < 128) { lm[tid >> 1][tid & 1] = 0u; lmT[tid >> 1][tid & 1] = 0u; }
        __syncthreads();
        #pragma unroll
        for (int r = 0; r < 4; ++r) {
            #pragma unroll
            for (int c = 0; c < 4; ++c) {
                int li = ty + 16 * r, lj = tx + 16 * c;
                int gi = ti * TS + li, gj = tj * TS + lj;
                bool bit = false;
                if (gi < gj) {
                    float ep = 1.0f / (1.0f + expf(-acc[r][c]));
                    float P = ep / epmax;
                    float Pc = fminf(fmaxf(P, 1e-6f), 1.0f - 1e-6f);
                    float uu = u[(size_t)gi * NN + gj];
                    float ucv = fminf(fmaxf(uu, 1e-6f), 1.0f - 1e-6f);
                    bit = Pc > (1.0f - ucv);
                } else if (gi == gj) {
                    bit = true;
                }
                if (bit) {
                    atomicOr(&lm[li][lj >> 5], 1u << (lj & 31));
                    atomicOr(&lmT[lj][li >> 5], 1u << (li & 31));
                }
            }
        }
        __syncthreads();
        if (tid < 128) {
            int r = tid >> 1, wq = tid & 1;
            unsigned word = lm[r][wq];
            if (ti == tj) word |= lmT[r][wq];
            mb[(size_t)(ti * TS + r) * 128 + tj * 2 + wq] = word;
        } else if (ti != tj) {
            int r = (tid - 128) >> 1, wq = tid & 1;
            mb[(size_t)(tj * TS + r) * 128 + ti * 2 + wq] = lmT[r][wq];
        }
    }
}

// Pass 1 (S-store path): compute tile, store S to ws, fold into global max.
__global__ __launch_bounds__(256, 4) void k_stile_store(const float* __restrict__ h,
                                                        float* __restrict__ S,
                                                        unsigned* __restrict__ smax_key) {
    int ti = blockIdx.y, tj = blockIdx.x;
    if (tj < ti) return;
    __shared__ float Ah[TS][68];
    __shared__ float Bh[TS][68];
    int tid = threadIdx.x;
    int tx = tid & 15, ty = tid >> 4;
    const float* ha = h + (size_t)ti * TS * 128;
    const float* hb = h + (size_t)tj * TS * 128;

    float acc[4][4];
    #pragma unroll
    for (int r = 0; r < 4; ++r)
        #pragma unroll
        for (int c = 0; c < 4; ++c) acc[r][c] = 0.0f;

    for (int half = 0; half < 2; ++half) {
        __syncthreads();
        #pragma unroll
        for (int t = 0; t < 4; ++t) {
            int f = tid + t * 256;
            int row = f >> 4, kk = f & 15;
            *(float4*)&Ah[row][kk * 4] = *(const float4*)(ha + (size_t)row * 128 + half * 64 + kk * 4);
            *(float4*)&Bh[row][kk * 4] = *(const float4*)(hb + (size_t)row * 128 + half * 64 + kk * 4);
        }
        __syncthreads();
        #pragma unroll 2
        for (int k4 = 0; k4 < 16; ++k4) {
            float4 a[4], b[4];
            #pragma unroll
            for (int r = 0; r < 4; ++r) a[r] = *(const float4*)&Ah[ty + 16 * r][k4 * 4];
            #pragma unroll
            for (int c = 0; c < 4; ++c) b[c] = *(const float4*)&Bh[tx + 16 * c][k4 * 4];
            #pragma unroll
            for (int r = 0; r < 4; ++r)
                #pragma unroll
                for (int c = 0; c < 4; ++c) {
                    acc[r][c] = fmaf(a[r].x, b[c].x, acc[r][c]);
                    acc[r][c] = fmaf(a[r].y, b[c].y, acc[r][c]);
                    acc[r][c] = fmaf(a[r].z, b[c].z, acc[r][c]);
                    acc[r][c] = fmaf(a[r].w, b[c].w, acc[r][c]);
                }
        }
    }

    float* sp = S + (size_t)(ti * 64 + tj) * 4096;
    #pragma unroll
    for (int r = 0; r < 4; ++r)
        #pragma unroll
        for (int c = 0; c < 4; ++c)
            sp[(ty + 16 * r) * 64 + tx + 16 * c] = acc[r][c];

    float m = -3.4e38f;
    #pragma unroll
    for (int r = 0; r < 4; ++r)
        #pragma unroll
        for (int c = 0; c < 4; ++c) m = fmaxf(m, acc[r][c]);
    #pragma unroll
    for (int o = 1; o < 64; o <<= 1) m = fmaxf(m, __shfl_xor(m, o, 64));
    __shared__ float wm[4];
    if ((tid & 63) == 0) wm[tid >> 6] = m;
    __syncthreads();
    if (tid == 0)
        atomicMax(smax_key, fkey(fmaxf(fmaxf(wm[0], wm[1]), fmaxf(wm[2], wm[3]))));
}

// Pass 2 (S-store path): read stored S, emit mask bits.
__global__ __launch_bounds__(256, 4) void k_bitemit(const float* __restrict__ S,
                                                    const float* __restrict__ u,
                                                    const unsigned* __restrict__ smax_key,
                                                    unsigned* __restrict__ mb) {
    int ti = blockIdx.y, tj = blockIdx.x;
    if (tj < ti) return;
    int tid = threadIdx.x;
    int tx = tid & 15, ty = tid >> 4;
    float smax = funkey(*smax_key);
    float epmax = 1.0f / (1.0f + expf(-smax));
    __shared__ unsigned lm[TS][2];
    __shared__ unsigned lmT[TS][2];
    if (tid < 128) { lm[tid >> 1][tid & 1] = 0u; lmT[tid >> 1][tid & 1] = 0u; }
    __syncthreads();
    const float* sp = S + (size_t)(ti * 64 + tj) * 4096;
    #pragma unroll
    for (int r = 0; r < 4; ++r) {
        #pragma unroll
        for (int c = 0; c < 4; ++c) {
            int li = ty + 16 * r, lj = tx + 16 * c;
            int gi = ti * TS + li, gj = tj * TS + lj;
            bool bit = false;
            if (gi < gj) {
                float ep = 1.0f / (1.0f + expf(-sp[li * 64 + lj]));
                float P = ep / epmax;
                float Pc = fminf(fmaxf(P, 1e-6f), 1.0f - 1e-6f);
                float uu = u[(size_t)gi * NN + gj];
                float ucv = fminf(fmaxf(uu, 1e-6f), 1.0f - 1e-6f);
                bit = Pc > (1.0f - ucv);
            } else if (gi == gj) {
                bit = true;
            }
            if (bit) {
                atomicOr(&lm[li][lj >> 5], 1u << (lj & 31));
                atomicOr(&lmT[lj][li >> 5], 1u << (li & 31));
            }
        }
    }
    __syncthreads();
    if (tid < 128) {
        int r = tid >> 1, wq = tid & 1;
        unsigned word = lm[r][wq];
        if (ti == tj) word |= lmT[r][wq];
        mb[(size_t)(ti * TS + r) * 128 + tj * 2 + wq] = word;
    } else if (ti != tj) {
        int r = (tid - 128) >> 1, wq = tid & 1;
        mb[(size_t)(tj * TS + r) * 128 + ti * 2 + wq] = lmT[r][wq];
    }
}

// Masked max, D=256, fp16-packed z; fp16-packed partial output.
// Round-19 inner loop (C++ sext; fastest of six variants) with JS=16 for
// occupancy: 4096 blocks halves per-block work, same total.
template<int RT, int JS>
__global__ __launch_bounds__(256, 8) void k_mmax256h(const unsigned* __restrict__ mb,
                                                     const unsigned* __restrict__ zh,
                                                     unsigned* __restrict__ pmh) {
    constexpr int JPS = NN / JS;   // 256 (JS=16)
    constexpr int WPS = JPS / 32;  // 8
    constexpr int RPG = RT / 4;    // 4
    constexpr int NRB = NN / RT;   // 256
    int rowblk = blockIdx.x % NRB, js = blockIdx.x / NRB;
    int i0 = rowblk * RT;

    __shared__ unsigned msk[RT][WPS + 1];
    {
        int t = threadIdx.x;
        if (t < RT * WPS)
            msk[t / WPS][t % WPS] = mb[(size_t)(i0 + t / WPS) * 128 + js * WPS + t % WPS];
    }
    __syncthreads();

    int d = threadIdx.x & 63;
    int g = threadIdx.x >> 6;
    const uint2* zbase = (const uint2*)zh + (size_t)js * JPS * 64 + d;   // row = 64 uint2

    uint2 acc[RPG];
    #pragma unroll
    for (int r = 0; r < RPG; ++r) acc[r] = make_uint2(0u, 0u);

    #pragma unroll 1
    for (int wq = 0; wq < WPS; ++wq) {
        unsigned m[RPG];
        #pragma unroll
        for (int r = 0; r < RPG; ++r)
            m[r] = (unsigned)__builtin_amdgcn_readfirstlane((int)msk[g * RPG + r][wq]);
        const uint2* zp = zbase + (size_t)(wq * 32) * 64;
        #pragma unroll 2
        for (int j4 = 0; j4 < 32; j4 += 4) {
            uint2 z0 = zp[0 * 64];
            uint2 z1 = zp[1 * 64];
            uint2 z2 = zp[2 * 64];
            uint2 z3 = zp[3 * 64];
            #pragma unroll
            for (int r = 0; r < RPG; ++r) {
                unsigned s0 = bit_sext_s(m[r], j4 + 0);
                unsigned s1 = bit_sext_s(m[r], j4 + 1);
                unsigned s2 = bit_sext_s(m[r], j4 + 2);
                unsigned s3 = bit_sext_s(m[r], j4 + 3);
                pkmax(acc[r].x, s0 & z0.x); pkmax(acc[r].y, s0 & z0.y);
                pkmax(acc[r].x, s1 & z1.x); pkmax(acc[r].y, s1 & z1.y);
                pkmax(acc[r].x, s2 & z2.x); pkmax(acc[r].y, s2 & z2.y);
                pkmax(acc[r].x, s3 & z3.x); pkmax(acc[r].y, s3 & z3.y);
            }
            zp += 4 * 64;
        }
    }

    uint2* po = (uint2*)(pmh + (size_t)js * NN * 128);   // row = 128 u32 = 64 uint2
    #pragma unroll
    for (int r = 0; r < RPG; ++r)
        po[(size_t)(i0 + g * RPG + r) * 64 + d] = acc[r];
}

// Masked max, D=128, fp16-packed z; fp16-packed partial output (round-20 form).
template<int RT, int JS>
__global__ __launch_bounds__(256, 8) void k_mmax128h(const unsigned* __restrict__ mb,
                                                     const unsigned* __restrict__ zh,
                                                     unsigned* __restrict__ pmh) {
    constexpr int JPS = NN / JS;   // 512
    constexpr int WPS = JPS / 32;  // 16
    constexpr int RPG = RT / 4;    // 4
    constexpr int NRB = NN / RT;   // 256
    int rowblk = blockIdx.x % NRB, js = blockIdx.x / NRB;
    int i0 = rowblk * RT;

    __shared__ unsigned msk[RT][WPS + 1];
    {
        int t = threadIdx.x;
        msk[t / WPS][t % WPS] = mb[(size_t)(i0 + t / WPS) * 128 + js * WPS + t % WPS];
    }
    __syncthreads();

    int lane = threadIdx.x & 63;
    int g = threadIdx.x >> 6;
    unsigned jpar = lane >> 5;
    int d2 = lane & 31;                 // uint2 index within row (32 uint2 = 64 u32)
    const uint2* zbase = (const uint2*)zh + (size_t)js * JPS * 32 + d2;

    uint2 acc[RPG];
    #pragma unroll
    for (int r = 0; r < RPG; ++r) acc[r] = make_uint2(0u, 0u);

    #pragma unroll 1
    for (int wq = 0; wq < WPS; ++wq) {
        unsigned m[RPG];
        #pragma unroll
        for (int r = 0; r < RPG; ++r)
            m[r] = (unsigned)__builtin_amdgcn_readfirstlane((int)msk[g * RPG + r][wq]);
        const uint2* zp = zbase + (size_t)(wq * 32) * 32;
        #pragma unroll 2
        for (int j4 = 0; j4 < 32; j4 += 4) {
            uint2 za = zp[(size_t)jpar * 32];
            uint2 zb = zp[(size_t)(2 + jpar) * 32];
            unsigned oa = (unsigned)j4 + jpar, ob = (unsigned)j4 + 2 + jpar;
            #pragma unroll
            for (int r = 0; r < RPG; ++r) {
                unsigned sa = vbfe1(m[r], oa);
                unsigned sb = vbfe1(m[r], ob);
                pkmax(acc[r].x, sa & za.x); pkmax(acc[r].y, sa & za.y);
                pkmax(acc[r].x, sb & zb.x); pkmax(acc[r].y, sb & zb.y);
            }
            zp += 4 * 32;
        }
    }

    #pragma unroll
    for (int r = 0; r < RPG; ++r) {
        unsigned ox = __shfl_xor(acc[r].x, 32, 64);
        unsigned oy = __shfl_xor(acc[r].y, 32, 64);
        pkmax(acc[r].x, ox);
        pkmax(acc[r].y, oy);
    }
    if (!jpar) {
        uint2* po = (uint2*)(pmh + (size_t)js * NN * 64);   // row = 64 u32 = 32 uint2
        #pragma unroll
        for (int r = 0; r < RPG; ++r)
            po[(size_t)(i0 + g * RPG + r) * 32 + d2] = acc[r];
    }
}

// Final 128->32 GEMM, NS fp16-packed partials, LDS-staged, 4 rows per block.
template<int NS>
__global__ void k_gemm_final(const unsigned* __restrict__ Xh, size_t xstride,
                             const float* __restrict__ W,
                             const float* __restrict__ b1, const float* __restrict__ b2,
                             float* __restrict__ out) {
    __shared__ float xr[4][128];
    int i0 = blockIdx.x * 4;
    for (int t = threadIdx.x; t < 256; t += 128) {
        int r = t >> 6, c = t & 63;
        size_t off = (size_t)(i0 + r) * 64 + c;
        unsigned v = Xh[off];
        #pragma unroll
        for (int s = 1; s < NS; ++s) pkmax(v, Xh[(size_t)s * xstride + off]);
        __half2 h = *(__half2*)&v;
        float2 f = __half22float2(h);
        xr[r][2 * c] = f.x;
        xr[r][2 * c + 1] = f.y;
    }
    __syncthreads();
    int il = threadIdx.x >> 5, j = threadIdx.x & 31;
    float acc = 0.0f;
    #pragma unroll 8
    for (int k = 0; k < 128; ++k) acc = fmaf(xr[il][k], W[k * 32 + j], acc);
    out[(size_t)(i0 + il) * 32 + j] = acc + b1[j] + b2[j];
}

extern "C" void kernel_launch(void* const* d_in, const int* in_sizes, int n_in,
                              void* d_out, int out_size, void* d_ws, size_t ws_size,
                              hipStream_t stream) {
    const float* inputs = (const float*)d_in[1];
    const float* feat   = (const float*)d_in[2];
    const float* u      = (const float*)d_in[3];
    const int*   src    = (const int*)d_in[4];
    const int*   dst    = (const int*)d_in[5];
    const float* gc0W = (const float*)d_in[6],  *gc0b = (const float*)d_in[7];
    const float* gc1W = (const float*)d_in[8],  *gc1b = (const float*)d_in[9];
    const float* p0W  = (const float*)d_in[10], *p0b  = (const float*)d_in[11];
    const float* l0W  = (const float*)d_in[12], *l0b  = (const float*)d_in[13];
    const float* b0   = (const float*)d_in[14];
    const float* p1W  = (const float*)d_in[15], *p1b  = (const float*)d_in[16];
    const float* l1W  = (const float*)d_in[17], *l1b  = (const float*)d_in[18];
    const float* b1   = (const float*)d_in[19];
    const float* p2W  = (const float*)d_in[20], *p2b  = (const float*)d_in[21];
    const float* l2W  = (const float*)d_in[22], *l2b  = (const float*)d_in[23];
    const float* b2   = (const float*)d_in[24];
    float* out = (float*)d_out;

    const size_t MB = 1048576;
    char* w = (char*)d_ws;
    int*      cnt_src  = (int*)(w + 0);            // 16 KB
    int*      cnt_dst  = (int*)(w + 16384);        // 16 KB
    float*    on       = (float*)(w + 32768);      // 16 KB
    float*    inn      = (float*)(w + 49152);      // 16 KB
    unsigned* smax_key = (unsigned*)(w + 65536);   // 4 B (padded)
    int*      cursor   = (int*)(w + 81920);        // 16 KB
    int*      eoff     = (int*)(w + 98304);        // 16.4 KB (4097 ints)
    char*     big      = w + 131072;
    float*    tmp      = (float*)(big);            // 2 MB
    int*      elist    = (int*)(big + 2 * MB);     // 512 KB
    float*    hbuf     = (float*)(big + 4 * MB);   // 2 MB
    unsigned* mb       = (unsigned*)(big + 6 * MB);// 2 MB
    unsigned* zh       = (unsigned*)(big + 8 * MB);// 2 MB (fp16-packed z)
    unsigned* pmh      = (unsigned*)(big + 12 * MB);// 32 MB (16 fp16 split partials)
    float*    hs       = (float*)(big + 44 * MB);  // 2 MB
    float*    Sbuf     = (float*)(big + 46 * MB);  // 64 MB
    bool use_sstore = ws_size >= 131072 + 110 * MB;

    hipMemsetAsync(w, 0, 131072, stream);
    k_count<<<EE / 256, 256, 0, stream>>>(src, dst, cnt_src, cnt_dst);
    k_norm<<<NN / 256, 256, 0, stream>>>(cnt_src, cnt_dst, on, inn);
    k_prefix<<<1, 1024, 0, stream>>>(cnt_dst, eoff);
    k_bucket<<<EE / 256, 256, 0, stream>>>(src, dst, eoff, cursor, elist);

    // --- GCN layer 0 ---
    k_gemm_scale<256, 128, 4><<<NN / 4, 128, 0, stream>>>(inputs, gc0W, on, tmp);
    k_gather<<<NN, 128, 0, stream>>>(tmp, elist, eoff, inn, gc0b, hbuf, 1);

    // --- GCN layer 1 ---
    k_gemm_scale<128, 128, 4><<<NN / 4, 128, 0, stream>>>(hbuf, gc1W, on, tmp);
    k_gather<<<NN, 128, 0, stream>>>(tmp, elist, eoff, inn, gc1b, hbuf, 0);

    // --- decode: S max + mask bits ---
    dim3 tg(64, 64);
    if (use_sstore) {
        k_stile_store<<<tg, 256, 0, stream>>>(hbuf, Sbuf, smax_key);
        k_bitemit<<<tg, 256, 0, stream>>>(Sbuf, u, smax_key, mb);
    } else {
        k_stile<0><<<tg, 256, 0, stream>>>(hbuf, nullptr, smax_key, nullptr);
        k_stile<1><<<tg, 256, 0, stream>>>(hbuf, u, smax_key, mb);
    }

    // --- GraphSAGE layer 0 (256 -> 128), fp16 masked max + fp16 partials ---
    k_gemm_ab<256, 256, 4, 1><<<NN / 4, 256, 0, stream>>>(feat, p0W, p0b, (float*)zh);
    k_mmax256h<16, 16><<<(NN / 16) * 16, 256, 0, stream>>>(mb, zh, pmh);
    k_gemm_mrgh<256, 128, 16, 4, 1><<<NN / 4, 128, 0, stream>>>(pmh, (size_t)NN * 128, l0W, l0b, b0, hs);

    // --- GraphSAGE layer 1 (128 -> 128) ---
    k_gemm_ab<128, 128, 4, 1><<<NN / 4, 128, 0, stream>>>(hs, p1W, p1b, (float*)zh);
    k_mmax128h<16, 8><<<(NN / 16) * 8, 256, 0, stream>>>(mb, zh, pmh);
    k_gemm_mrgh<128, 128, 8, 4, 1><<<NN / 4, 128, 0, stream>>>(pmh, (size_t)NN * 64, l1W, l1b, b1, tmp);

    // --- GraphSAGE layer 2 (128 -> 32) ---
    k_gemm_ab<128, 128, 4, 1><<<NN / 4, 128, 0, stream>>>(tmp, p2W, p2b, (float*)zh);
    k_mmax128h<16, 8><<<(NN / 16) * 8, 256, 0, stream>>>(mb, zh, pmh);
    k_gemm_final<8><<<NN / 4, 128, 0, stream>>>(pmh, (size_t)NN * 64, l2W, l2b, b2, out);
}

// Round 22
// 543.248 us; speedup vs baseline: 1.4318x; 1.0064x over previous
//
#include <hip/hip_runtime.h>
#include <hip/hip_fp16.h>
#include <cstdint>
#include <cstddef>

#define NN 4096
#define EE 131072
#define TS 64

__device__ __forceinline__ unsigned fkey(float f) {
    unsigned u = __float_as_uint(f);
    return (u & 0x80000000u) ? ~u : (u | 0x80000000u);
}
__device__ __forceinline__ float funkey(unsigned k) {
    unsigned u = (k & 0x80000000u) ? (k & 0x7fffffffu) : ~k;
    return __uint_as_float(u);
}

// ---- asm pins (VALU-only; proven safe rounds 14-21) ----
__device__ __forceinline__ void pkmax(unsigned& a, unsigned x) {
    asm("v_pk_max_f16 %0, %0, %1" : "+v"(a) : "v"(x));
}
__device__ __forceinline__ unsigned vbfe1(unsigned m, unsigned off) {
    unsigned t;
    asm("v_bfe_i32 %0, %1, %2, 1" : "=v"(t) : "s"(m), "v"(off));
    return t;
}
__device__ __forceinline__ unsigned bit_sext_s(unsigned w, int off) {
    return (unsigned)(((int)(w << (31 - off))) >> 31);
}

__global__ void k_count(const int* __restrict__ src, const int* __restrict__ dst,
                        int* __restrict__ cs, int* __restrict__ cd) {
    int e = blockIdx.x * 256 + threadIdx.x;
    if (e < EE) {
        atomicAdd(&cs[src[e]], 1);
        atomicAdd(&cd[dst[e]], 1);
    }
}

__global__ void k_norm(const int* __restrict__ cs, const int* __restrict__ cd,
                       float* __restrict__ on, float* __restrict__ inn) {
    int i = blockIdx.x * 256 + threadIdx.x;
    if (i < NN) {
        int a = cs[i] > 1 ? cs[i] : 1;
        int b = cd[i] > 1 ? cd[i] : 1;
        on[i]  = 1.0f / sqrtf((float)a);
        inn[i] = 1.0f / sqrtf((float)b);
    }
}

// Exclusive prefix sum of cnt_dst (4096) -> off[0..4096]. One block, 1024 thr.
__global__ void k_prefix(const int* __restrict__ cnt, int* __restrict__ off) {
    __shared__ int ls[1024];
    int t = threadIdx.x;
    int base[4];
    int s = 0;
    #pragma unroll
    for (int k = 0; k < 4; ++k) { base[k] = s; s += cnt[t * 4 + k]; }
    ls[t] = s;
    __syncthreads();
    for (int o = 1; o < 1024; o <<= 1) {
        int v = (t >= o) ? ls[t - o] : 0;
        __syncthreads();
        ls[t] += v;
        __syncthreads();
    }
    int excl = (t == 0) ? 0 : ls[t - 1];
    #pragma unroll
    for (int k = 0; k < 4; ++k) off[t * 4 + k] = excl + base[k];
    if (t == 1023) off[4096] = ls[1023];
}

// Bucket edges by dst: elist[off[d] + cursor[d]++] = src.
__global__ void k_bucket(const int* __restrict__ src, const int* __restrict__ dst,
                         const int* __restrict__ off, int* __restrict__ cursor,
                         int* __restrict__ elist) {
    int e = blockIdx.x * 256 + threadIdx.x;
    if (e < EE) {
        int d = dst[e];
        int pos = atomicAdd(&cursor[d], 1);
        elist[off[d] + pos] = src[e];
    }
}

// CSR gather segment-sum + GCN epilogue.
__global__ void k_gather(const float* __restrict__ t, const int* __restrict__ elist,
                         const int* __restrict__ off, const float* __restrict__ inn,
                         const float* __restrict__ b, float* __restrict__ outp,
                         int do_relu) {
    int d = blockIdx.x;
    int j = threadIdx.x;
    int s0 = off[d], s1 = off[d + 1];
    float a0 = 0.f, a1 = 0.f, a2 = 0.f, a3 = 0.f;
    int e = s0;
    for (; e + 4 <= s1; e += 4) {
        a0 += t[(size_t)elist[e + 0] * 128 + j];
        a1 += t[(size_t)elist[e + 1] * 128 + j];
        a2 += t[(size_t)elist[e + 2] * 128 + j];
        a3 += t[(size_t)elist[e + 3] * 128 + j];
    }
    for (; e < s1; ++e) a0 += t[(size_t)elist[e] * 128 + j];
    float v = ((a0 + a1) + (a2 + a3)) * inn[d] + b[j];
    if (do_relu) v = fmaxf(v, 0.0f);
    outp[(size_t)d * 128 + j] = v;
}

// RB rows per block: W[k][j] read once per block for RB rows.
template<int K, int ND, int RB>
__global__ void k_gemm_scale(const float* __restrict__ X, const float* __restrict__ W,
                             const float* __restrict__ scale, float* __restrict__ out) {
    __shared__ float xr[RB][K];
    int i0 = blockIdx.x * RB;
    for (int t = threadIdx.x; t < RB * K; t += ND)
        xr[t / K][t % K] = X[(size_t)(i0 + t / K) * K + t % K];
    __syncthreads();
    int j = threadIdx.x;
    float acc[RB];
    #pragma unroll
    for (int r = 0; r < RB; ++r) acc[r] = 0.0f;
    #pragma unroll 4
    for (int k = 0; k < K; ++k) {
        float w = W[k * ND + j];
        #pragma unroll
        for (int r = 0; r < RB; ++r) acc[r] = fmaf(xr[r][k], w, acc[r]);
    }
    #pragma unroll
    for (int r = 0; r < RB; ++r)
        out[(size_t)(i0 + r) * ND + j] = acc[r] * scale[i0 + r];
}

// f32-input GEMM, RB rows/block. H16=1: relu + packed-half2 output.
template<int K, int ND, int RB, int H16>
__global__ void k_gemm_ab(const float* __restrict__ X, const float* __restrict__ W,
                          const float* __restrict__ b1, float* __restrict__ out) {
    __shared__ float xr[RB][K];
    int i0 = blockIdx.x * RB;
    for (int t = threadIdx.x; t < RB * K; t += ND)
        xr[t / K][t % K] = X[(size_t)(i0 + t / K) * K + t % K];
    __syncthreads();
    int j = threadIdx.x;
    float acc[RB];
    #pragma unroll
    for (int r = 0; r < RB; ++r) acc[r] = 0.0f;
    #pragma unroll 4
    for (int k = 0; k < K; ++k) {
        float w = W[k * ND + j];
        #pragma unroll
        for (int r = 0; r < RB; ++r) acc[r] = fmaf(xr[r][k], w, acc[r]);
    }
    if constexpr (H16) {
        unsigned* oh = (unsigned*)out;
        #pragma unroll
        for (int r = 0; r < RB; ++r) {
            float v = fmaxf(acc[r] + b1[j], 0.0f);
            float o2 = __shfl_xor(v, 1, 64);
            if ((j & 1) == 0) {
                __half2 h = __floats2half2_rn(v, o2);
                oh[(size_t)(i0 + r) * (ND / 2) + (j >> 1)] = *(unsigned*)&h;
            }
        }
    } else {
        #pragma unroll
        for (int r = 0; r < RB; ++r)
            out[(size_t)(i0 + r) * ND + j] = acc[r] + b1[j];
    }
}

// Merge GEMM from NS fp16-packed partials (packed pkmax merge, lossless),
// then f32 GEMM. L2N=1: fused relu + l2-normalize epilogue.
template<int K, int ND, int NS, int RB, int L2N>
__global__ void k_gemm_mrgh(const unsigned* __restrict__ Xh, size_t xstride,
                            const float* __restrict__ W,
                            const float* __restrict__ b1, const float* __restrict__ b2,
                            float* __restrict__ out) {
    __shared__ float xr[RB][K];
    int i0 = blockIdx.x * RB;
    for (int t = threadIdx.x; t < RB * (K / 2); t += ND) {
        int r = t / (K / 2), c = t % (K / 2);
        size_t off = (size_t)(i0 + r) * (K / 2) + c;
        unsigned v = Xh[off];
        #pragma unroll
        for (int s = 1; s < NS; ++s) pkmax(v, Xh[(size_t)s * xstride + off]);
        __half2 h = *(__half2*)&v;
        float2 f = __half22float2(h);
        xr[r][2 * c] = f.x;
        xr[r][2 * c + 1] = f.y;
    }
    __syncthreads();
    int j = threadIdx.x;
    float acc[RB];
    #pragma unroll
    for (int r = 0; r < RB; ++r) acc[r] = 0.0f;
    #pragma unroll 4
    for (int k = 0; k < K; ++k) {
        float w = W[k * ND + j];
        #pragma unroll
        for (int r = 0; r < RB; ++r) acc[r] = fmaf(xr[r][k], w, acc[r]);
    }
    if constexpr (L2N) {
        float v[RB], ss[RB];
        #pragma unroll
        for (int r = 0; r < RB; ++r) {
            float t = acc[r] + b1[j];
            if (b2) t += b2[j];
            v[r] = fmaxf(t, 0.0f);
            ss[r] = v[r] * v[r];
        }
        #pragma unroll
        for (int o = 1; o < 64; o <<= 1)
            #pragma unroll
            for (int r = 0; r < RB; ++r) ss[r] += __shfl_xor(ss[r], o, 64);
        __shared__ float sred[RB][2];
        if ((threadIdx.x & 63) == 0)
            #pragma unroll
            for (int r = 0; r < RB; ++r) sred[r][threadIdx.x >> 6] = ss[r];
        __syncthreads();
        #pragma unroll
        for (int r = 0; r < RB; ++r) {
            float tot = sred[r][0] + sred[r][1];
            out[(size_t)(i0 + r) * ND + j] = v[r] / fmaxf(sqrtf(tot), 1e-12f);
        }
    } else {
        #pragma unroll
        for (int r = 0; r < RB; ++r) {
            float v = acc[r] + b1[j];
            if (b2) v += b2[j];
            out[(size_t)(i0 + r) * ND + j] = v;
        }
    }
}

// ---- S = h h^T 64x64 tile; MODE 0: max-only; MODE 1: recompute + bit-emit ----
template<int MODE>
__global__ __launch_bounds__(256, 4) void k_stile(const float* __restrict__ h,
                                                  const float* __restrict__ u,
                                                  unsigned* __restrict__ smax_key,
                                                  unsigned* __restrict__ mb) {
    int ti = blockIdx.y, tj = blockIdx.x;
    if (tj < ti) return;
    __shared__ float Ah[TS][68];
    __shared__ float Bh[TS][68];
    int tid = threadIdx.x;
    int tx = tid & 15, ty = tid >> 4;
    const float* ha = h + (size_t)ti * TS * 128;
    const float* hb = h + (size_t)tj * TS * 128;

    float acc[4][4];
    #pragma unroll
    for (int r = 0; r < 4; ++r)
        #pragma unroll
        for (int c = 0; c < 4; ++c) acc[r][c] = 0.0f;

    for (int half = 0; half < 2; ++half) {
        __syncthreads();
        #pragma unroll
        for (int t = 0; t < 4; ++t) {
            int f = tid + t * 256;
            int row = f >> 4, kk = f & 15;
            *(float4*)&Ah[row][kk * 4] = *(const float4*)(ha + (size_t)row * 128 + half * 64 + kk * 4);
            *(float4*)&Bh[row][kk * 4] = *(const float4*)(hb + (size_t)row * 128 + half * 64 + kk * 4);
        }
        __syncthreads();
        #pragma unroll 2
        for (int k4 = 0; k4 < 16; ++k4) {
            float4 a[4], b[4];
            #pragma unroll
            for (int r = 0; r < 4; ++r) a[r] = *(const float4*)&Ah[ty + 16 * r][k4 * 4];
            #pragma unroll
            for (int c = 0; c < 4; ++c) b[c] = *(const float4*)&Bh[tx + 16 * c][k4 * 4];
            #pragma unroll
            for (int r = 0; r < 4; ++r)
                #pragma unroll
                for (int c = 0; c < 4; ++c) {
                    acc[r][c] = fmaf(a[r].x, b[c].x, acc[r][c]);
                    acc[r][c] = fmaf(a[r].y, b[c].y, acc[r][c]);
                    acc[r][c] = fmaf(a[r].z, b[c].z, acc[r][c]);
                    acc[r][c] = fmaf(a[r].w, b[c].w, acc[r][c]);
                }
        }
    }

    if constexpr (MODE == 0) {
        float m = -3.4e38f;
        #pragma unroll
        for (int r = 0; r < 4; ++r)
            #pragma unroll
            for (int c = 0; c < 4; ++c) m = fmaxf(m, acc[r][c]);
        #pragma unroll
        for (int o = 1; o < 64; o <<= 1) m = fmaxf(m, __shfl_xor(m, o, 64));
        __shared__ float wm[4];
        if ((tid & 63) == 0) wm[tid >> 6] = m;
        __syncthreads();
        if (tid == 0) {
            float mm = fmaxf(fmaxf(wm[0], wm[1]), fmaxf(wm[2], wm[3]));
            atomicMax(smax_key, fkey(mm));
        }
    } else {
        float smax = funkey(*smax_key);
        float epmax = 1.0f / (1.0f + expf(-smax));
        __shared__ unsigned lm[TS][2];
        __shared__ unsigned lmT[TS][2];
        if (tid < 128) { lm[tid >> 1][tid & 1] = 0u; lmT[tid >> 1][tid & 1] = 0u; }
        __syncthreads();
        #pragma unroll
        for (int r = 0; r < 4; ++r) {
            #pragma unroll
            for (int c = 0; c < 4; ++c) {
                int li = ty + 16 * r, lj = tx + 16 * c;
                int gi = ti * TS + li, gj = tj * TS + lj;
                bool bit = false;
                if (gi < gj) {
                    float ep = 1.0f / (1.0f + expf(-acc[r][c]));
                    float P = ep / epmax;
                    float Pc = fminf(fmaxf(P, 1e-6f), 1.0f - 1e-6f);
                    float uu = u[(size_t)gi * NN + gj];
                    float ucv = fminf(fmaxf(uu, 1e-6f), 1.0f - 1e-6f);
                    bit = Pc > (1.0f - ucv);
                } else if (gi == gj) {
                    bit = true;
                }
                if (bit) {
                    atomicOr(&lm[li][lj >> 5], 1u << (lj & 31));
                    atomicOr(&lmT[lj][li >> 5], 1u << (li & 31));
                }
            }
        }
        __syncthreads();
        if (tid < 128) {
            int r = tid >> 1, wq = tid & 1;
            unsigned word = lm[r][wq];
            if (ti == tj) word |= lmT[r][wq];
            mb[(size_t)(ti * TS + r) * 128 + tj * 2 + wq] = word;
        } else if (ti != tj) {
            int r = (tid - 128) >> 1, wq = tid & 1;
            mb[(size_t)(tj * TS + r) * 128 + ti * 2 + wq] = lmT[r][wq];
        }
    }
}

// Pass 1 (S-store path): compute tile, store S to ws, fold into global max.
__global__ __launch_bounds__(256, 4) void k_stile_store(const float* __restrict__ h,
                                                        float* __restrict__ S,
                                                        unsigned* __restrict__ smax_key) {
    int ti = blockIdx.y, tj = blockIdx.x;
    if (tj < ti) return;
    __shared__ float Ah[TS][68];
    __shared__ float Bh[TS][68];
    int tid = threadIdx.x;
    int tx = tid & 15, ty = tid >> 4;
    const float* ha = h + (size_t)ti * TS * 128;
    const float* hb = h + (size_t)tj * TS * 128;

    float acc[4][4];
    #pragma unroll
    for (int r = 0; r < 4; ++r)
        #pragma unroll
        for (int c = 0; c < 4; ++c) acc[r][c] = 0.0f;

    for (int half = 0; half < 2; ++half) {
        __syncthreads();
        #pragma unroll
        for (int t = 0; t < 4; ++t) {
            int f = tid + t * 256;
            int row = f >> 4, kk = f & 15;
            *(float4*)&Ah[row][kk * 4] = *(const float4*)(ha + (size_t)row * 128 + half * 64 + kk * 4);
            *(float4*)&Bh[row][kk * 4] = *(const float4*)(hb + (size_t)row * 128 + half * 64 + kk * 4);
        }
        __syncthreads();
        #pragma unroll 2
        for (int k4 = 0; k4 < 16; ++k4) {
            float4 a[4], b[4];
            #pragma unroll
            for (int r = 0; r < 4; ++r) a[r] = *(const float4*)&Ah[ty + 16 * r][k4 * 4];
            #pragma unroll
            for (int c = 0; c < 4; ++c) b[c] = *(const float4*)&Bh[tx + 16 * c][k4 * 4];
            #pragma unroll
            for (int r = 0; r < 4; ++r)
                #pragma unroll
                for (int c = 0; c < 4; ++c) {
                    acc[r][c] = fmaf(a[r].x, b[c].x, acc[r][c]);
                    acc[r][c] = fmaf(a[r].y, b[c].y, acc[r][c]);
                    acc[r][c] = fmaf(a[r].z, b[c].z, acc[r][c]);
                    acc[r][c] = fmaf(a[r].w, b[c].w, acc[r][c]);
                }
        }
    }

    float* sp = S + (size_t)(ti * 64 + tj) * 4096;
    #pragma unroll
    for (int r = 0; r < 4; ++r)
        #pragma unroll
        for (int c = 0; c < 4; ++c)
            sp[(ty + 16 * r) * 64 + tx + 16 * c] = acc[r][c];

    float m = -3.4e38f;
    #pragma unroll
    for (int r = 0; r < 4; ++r)
        #pragma unroll
        for (int c = 0; c < 4; ++c) m = fmaxf(m, acc[r][c]);
    #pragma unroll
    for (int o = 1; o < 64; o <<= 1) m = fmaxf(m, __shfl_xor(m, o, 64));
    __shared__ float wm[4];
    if ((tid & 63) == 0) wm[tid >> 6] = m;
    __syncthreads();
    if (tid == 0)
        atomicMax(smax_key, fkey(fmaxf(fmaxf(wm[0], wm[1]), fmaxf(wm[2], wm[3]))));
}

// Pass 2 (S-store path): read stored S, emit mask bits.
__global__ __launch_bounds__(256, 4) void k_bitemit(const float* __restrict__ S,
                                                    const float* __restrict__ u,
                                                    const unsigned* __restrict__ smax_key,
                                                    unsigned* __restrict__ mb) {
    int ti = blockIdx.y, tj = blockIdx.x;
    if (tj < ti) return;
    int tid = threadIdx.x;
    int tx = tid & 15, ty = tid >> 4;
    float smax = funkey(*smax_key);
    float epmax = 1.0f / (1.0f + expf(-smax));
    __shared__ unsigned lm[TS][2];
    __shared__ unsigned lmT[TS][2];
    if (tid < 128) { lm[tid >> 1][tid & 1] = 0u; lmT[tid >> 1][tid & 1] = 0u; }
    __syncthreads();
    const float* sp = S + (size_t)(ti * 64 + tj) * 4096;
    #pragma unroll
    for (int r = 0; r < 4; ++r) {
        #pragma unroll
        for (int c = 0; c < 4; ++c) {
            int li = ty + 16 * r, lj = tx + 16 * c;
            int gi = ti * TS + li, gj = tj * TS + lj;
            bool bit = false;
            if (gi < gj) {
                float ep = 1.0f / (1.0f + expf(-sp[li * 64 + lj]));
                float P = ep / epmax;
                float Pc = fminf(fmaxf(P, 1e-6f), 1.0f - 1e-6f);
                float uu = u[(size_t)gi * NN + gj];
                float ucv = fminf(fmaxf(uu, 1e-6f), 1.0f - 1e-6f);
                bit = Pc > (1.0f - ucv);
            } else if (gi == gj) {
                bit = true;
            }
            if (bit) {
                atomicOr(&lm[li][lj >> 5], 1u << (lj & 31));
                atomicOr(&lmT[lj][li >> 5], 1u << (li & 31));
            }
        }
    }
    __syncthreads();
    if (tid < 128) {
        int r = tid >> 1, wq = tid & 1;
        unsigned word = lm[r][wq];
        if (ti == tj) word |= lmT[r][wq];
        mb[(size_t)(ti * TS + r) * 128 + tj * 2 + wq] = word;
    } else if (ti != tj) {
        int r = (tid - 128) >> 1, wq = tid & 1;
        mb[(size_t)(tj * TS + r) * 128 + ti * 2 + wq] = lmT[r][wq];
    }
}

// Masked max, D=256, fp16-packed z; fp16-packed partial output. JS=16.
template<int RT, int JS>
__global__ __launch_bounds__(256, 8) void k_mmax256h(const unsigned* __restrict__ mb,
                                                     const unsigned* __restrict__ zh,
                                                     unsigned* __restrict__ pmh) {
    constexpr int JPS = NN / JS;   // 256 (JS=16)
    constexpr int WPS = JPS / 32;  // 8
    constexpr int RPG = RT / 4;    // 4
    constexpr int NRB = NN / RT;   // 256
    int rowblk = blockIdx.x % NRB, js = blockIdx.x / NRB;
    int i0 = rowblk * RT;

    __shared__ unsigned msk[RT][WPS + 1];
    {
        int t = threadIdx.x;
        if (t < RT * WPS)
            msk[t / WPS][t % WPS] = mb[(size_t)(i0 + t / WPS) * 128 + js * WPS + t % WPS];
    }
    __syncthreads();

    int d = threadIdx.x & 63;
    int g = threadIdx.x >> 6;
    const uint2* zbase = (const uint2*)zh + (size_t)js * JPS * 64 + d;   // row = 64 uint2

    uint2 acc[RPG];
    #pragma unroll
    for (int r = 0; r < RPG; ++r) acc[r] = make_uint2(0u, 0u);

    #pragma unroll 1
    for (int wq = 0; wq < WPS; ++wq) {
        unsigned m[RPG];
        #pragma unroll
        for (int r = 0; r < RPG; ++r)
            m[r] = (unsigned)__builtin_amdgcn_readfirstlane((int)msk[g * RPG + r][wq]);
        const uint2* zp = zbase + (size_t)(wq * 32) * 64;
        #pragma unroll 2
        for (int j4 = 0; j4 < 32; j4 += 4) {
            uint2 z0 = zp[0 * 64];
            uint2 z1 = zp[1 * 64];
            uint2 z2 = zp[2 * 64];
            uint2 z3 = zp[3 * 64];
            #pragma unroll
            for (int r = 0; r < RPG; ++r) {
                unsigned s0 = bit_sext_s(m[r], j4 + 0);
                unsigned s1 = bit_sext_s(m[r], j4 + 1);
                unsigned s2 = bit_sext_s(m[r], j4 + 2);
                unsigned s3 = bit_sext_s(m[r], j4 + 3);
                pkmax(acc[r].x, s0 & z0.x); pkmax(acc[r].y, s0 & z0.y);
                pkmax(acc[r].x, s1 & z1.x); pkmax(acc[r].y, s1 & z1.y);
                pkmax(acc[r].x, s2 & z2.x); pkmax(acc[r].y, s2 & z2.y);
                pkmax(acc[r].x, s3 & z3.x); pkmax(acc[r].y, s3 & z3.y);
            }
            zp += 4 * 64;
        }
    }

    uint2* po = (uint2*)(pmh + (size_t)js * NN * 128);   // row = 128 u32 = 64 uint2
    #pragma unroll
    for (int r = 0; r < RPG; ++r)
        po[(size_t)(i0 + g * RPG + r) * 64 + d] = acc[r];
}

// Masked max, D=128, fp16-packed z; fp16-packed partial output. JS=16.
template<int RT, int JS>
__global__ __launch_bounds__(256, 8) void k_mmax128h(const unsigned* __restrict__ mb,
                                                     const unsigned* __restrict__ zh,
                                                     unsigned* __restrict__ pmh) {
    constexpr int JPS = NN / JS;   // 256 (JS=16)
    constexpr int WPS = JPS / 32;  // 8
    constexpr int RPG = RT / 4;    // 4
    constexpr int NRB = NN / RT;   // 256
    int rowblk = blockIdx.x % NRB, js = blockIdx.x / NRB;
    int i0 = rowblk * RT;

    __shared__ unsigned msk[RT][WPS + 1];
    {
        int t = threadIdx.x;
        if (t < RT * WPS)
            msk[t / WPS][t % WPS] = mb[(size_t)(i0 + t / WPS) * 128 + js * WPS + t % WPS];
    }
    __syncthreads();

    int lane = threadIdx.x & 63;
    int g = threadIdx.x >> 6;
    unsigned jpar = lane >> 5;
    int d2 = lane & 31;                 // uint2 index within row (32 uint2 = 64 u32)
    const uint2* zbase = (const uint2*)zh + (size_t)js * JPS * 32 + d2;

    uint2 acc[RPG];
    #pragma unroll
    for (int r = 0; r < RPG; ++r) acc[r] = make_uint2(0u, 0u);

    #pragma unroll 1
    for (int wq = 0; wq < WPS; ++wq) {
        unsigned m[RPG];
        #pragma unroll
        for (int r = 0; r < RPG; ++r)
            m[r] = (unsigned)__builtin_amdgcn_readfirstlane((int)msk[g * RPG + r][wq]);
        const uint2* zp = zbase + (size_t)(wq * 32) * 32;
        #pragma unroll 2
        for (int j4 = 0; j4 < 32; j4 += 4) {
            uint2 za = zp[(size_t)jpar * 32];
            uint2 zb = zp[(size_t)(2 + jpar) * 32];
            unsigned oa = (unsigned)j4 + jpar, ob = (unsigned)j4 + 2 + jpar;
            #pragma unroll
            for (int r = 0; r < RPG; ++r) {
                unsigned sa = vbfe1(m[r], oa);
                unsigned sb = vbfe1(m[r], ob);
                pkmax(acc[r].x, sa & za.x); pkmax(acc[r].y, sa & za.y);
                pkmax(acc[r].x, sb & zb.x); pkmax(acc[r].y, sb & zb.y);
            }
            zp += 4 * 32;
        }
    }

    #pragma unroll
    for (int r = 0; r < RPG; ++r) {
        unsigned ox = __shfl_xor(acc[r].x, 32, 64);
        unsigned oy = __shfl_xor(acc[r].y, 32, 64);
        pkmax(acc[r].x, ox);
        pkmax(acc[r].y, oy);
    }
    if (!jpar) {
        uint2* po = (uint2*)(pmh + (size_t)js * NN * 64);   // row = 64 u32 = 32 uint2
        #pragma unroll
        for (int r = 0; r < RPG; ++r)
            po[(size_t)(i0 + g * RPG + r) * 32 + d2] = acc[r];
    }
}

// Final 128->32 GEMM, NS fp16-packed partials, LDS-staged, 4 rows per block.
template<int NS>
__global__ void k_gemm_final(const unsigned* __restrict__ Xh, size_t xstride,
                             const float* __restrict__ W,
                             const float* __restrict__ b1, const float* __restrict__ b2,
                             float* __restrict__ out) {
    __shared__ float xr[4][128];
    int i0 = blockIdx.x * 4;
    for (int t = threadIdx.x; t < 256; t += 128) {
        int r = t >> 6, c = t & 63;
        size_t off = (size_t)(i0 + r) * 64 + c;
        unsigned v = Xh[off];
        #pragma unroll
        for (int s = 1; s < NS; ++s) pkmax(v, Xh[(size_t)s * xstride + off]);
        __half2 h = *(__half2*)&v;
        float2 f = __half22float2(h);
        xr[r][2 * c] = f.x;
        xr[r][2 * c + 1] = f.y;
    }
    __syncthreads();
    int il = threadIdx.x >> 5, j = threadIdx.x & 31;
    float acc = 0.0f;
    #pragma unroll 8
    for (int k = 0; k < 128; ++k) acc = fmaf(xr[il][k], W[k * 32 + j], acc);
    out[(size_t)(i0 + il) * 32 + j] = acc + b1[j] + b2[j];
}

extern "C" void kernel_launch(void* const* d_in, const int* in_sizes, int n_in,
                              void* d_out, int out_size, void* d_ws, size_t ws_size,
                              hipStream_t stream) {
    const float* inputs = (const float*)d_in[1];
    const float* feat   = (const float*)d_in[2];
    const float* u      = (const float*)d_in[3];
    const int*   src    = (const int*)d_in[4];
    const int*   dst    = (const int*)d_in[5];
    const float* gc0W = (const float*)d_in[6],  *gc0b = (const float*)d_in[7];
    const float* gc1W = (const float*)d_in[8],  *gc1b = (const float*)d_in[9];
    const float* p0W  = (const float*)d_in[10], *p0b  = (const float*)d_in[11];
    const float* l0W  = (const float*)d_in[12], *l0b  = (const float*)d_in[13];
    const float* b0   = (const float*)d_in[14];
    const float* p1W  = (const float*)d_in[15], *p1b  = (const float*)d_in[16];
    const float* l1W  = (const float*)d_in[17], *l1b  = (const float*)d_in[18];
    const float* b1   = (const float*)d_in[19];
    const float* p2W  = (const float*)d_in[20], *p2b  = (const float*)d_in[21];
    const float* l2W  = (const float*)d_in[22], *l2b  = (const float*)d_in[23];
    const float* b2   = (const float*)d_in[24];
    float* out = (float*)d_out;

    const size_t MB = 1048576;
    char* w = (char*)d_ws;
    int*      cnt_src  = (int*)(w + 0);            // 16 KB
    int*      cnt_dst  = (int*)(w + 16384);        // 16 KB
    float*    on       = (float*)(w + 32768);      // 16 KB
    float*    inn      = (float*)(w + 49152);      // 16 KB
    unsigned* smax_key = (unsigned*)(w + 65536);   // 4 B (padded)
    int*      cursor   = (int*)(w + 81920);        // 16 KB
    int*      eoff     = (int*)(w + 98304);        // 16.4 KB (4097 ints)
    char*     big      = w + 131072;
    float*    tmp      = (float*)(big);            // 2 MB
    int*      elist    = (int*)(big + 2 * MB);     // 512 KB
    float*    hbuf     = (float*)(big + 4 * MB);   // 2 MB
    unsigned* mb       = (unsigned*)(big + 6 * MB);// 2 MB
    unsigned* zh       = (unsigned*)(big + 8 * MB);// 2 MB (fp16-packed z)
    unsigned* pmh      = (unsigned*)(big + 12 * MB);// 32 MB (16 fp16 split partials)
    float*    hs       = (float*)(big + 44 * MB);  // 2 MB
    float*    Sbuf     = (float*)(big + 46 * MB);  // 64 MB
    bool use_sstore = ws_size >= 131072 + 110 * MB;

    hipMemsetAsync(w, 0, 131072, stream);
    k_count<<<EE / 256, 256, 0, stream>>>(src, dst, cnt_src, cnt_dst);
    k_norm<<<NN / 256, 256, 0, stream>>>(cnt_src, cnt_dst, on, inn);
    k_prefix<<<1, 1024, 0, stream>>>(cnt_dst, eoff);
    k_bucket<<<EE / 256, 256, 0, stream>>>(src, dst, eoff, cursor, elist);

    // --- GCN layer 0 ---
    k_gemm_scale<256, 128, 4><<<NN / 4, 128, 0, stream>>>(inputs, gc0W, on, tmp);
    k_gather<<<NN, 128, 0, stream>>>(tmp, elist, eoff, inn, gc0b, hbuf, 1);

    // --- GCN layer 1 ---
    k_gemm_scale<128, 128, 4><<<NN / 4, 128, 0, stream>>>(hbuf, gc1W, on, tmp);
    k_gather<<<NN, 128, 0, stream>>>(tmp, elist, eoff, inn, gc1b, hbuf, 0);

    // --- decode: S max + mask bits ---
    dim3 tg(64, 64);
    if (use_sstore) {
        k_stile_store<<<tg, 256, 0, stream>>>(hbuf, Sbuf, smax_key);
        k_bitemit<<<tg, 256, 0, stream>>>(Sbuf, u, smax_key, mb);
    } else {
        k_stile<0><<<tg, 256, 0, stream>>>(hbuf, nullptr, smax_key, nullptr);
        k_stile<1><<<tg, 256, 0, stream>>>(hbuf, u, smax_key, mb);
    }

    // --- GraphSAGE layer 0 (256 -> 128), fp16 masked max + fp16 partials ---
    k_gemm_ab<256, 256, 4, 1><<<NN / 4, 256, 0, stream>>>(feat, p0W, p0b, (float*)zh);
    k_mmax256h<16, 16><<<(NN / 16) * 16, 256, 0, stream>>>(mb, zh, pmh);
    k_gemm_mrgh<256, 128, 16, 4, 1><<<NN / 4, 128, 0, stream>>>(pmh, (size_t)NN * 128, l0W, l0b, b0, hs);

    // --- GraphSAGE layer 1 (128 -> 128) ---
    k_gemm_ab<128, 128, 4, 1><<<NN / 4, 128, 0, stream>>>(hs, p1W, p1b, (float*)zh);
    k_mmax128h<16, 16><<<(NN / 16) * 16, 256, 0, stream>>>(mb, zh, pmh);
    k_gemm_mrgh<128, 128, 16, 4, 1><<<NN / 4, 128, 0, stream>>>(pmh, (size_t)NN * 64, l1W, l1b, b1, tmp);

    // --- GraphSAGE layer 2 (128 -> 32) ---
    k_gemm_ab<128, 128, 4, 1><<<NN / 4, 128, 0, stream>>>(tmp, p2W, p2b, (float*)zh);
    k_mmax128h<16, 16><<<(NN / 16) * 16, 256, 0, stream>>>(mb, zh, pmh);
    k_gemm_final<16><<<NN / 4, 128, 0, stream>>>(pmh, (size_t)NN * 64, l2W, l2b, b2, out);
}